// Round 9
// baseline (9688.008 us; speedup 1.0000x reference)
//
#include <hip/hip_runtime.h>
#include <hip/hip_bf16.h>

#define NCL   300000
#define NLIT  200000
#define HALFL 100000
#define NVAR  100000

#define NB_C  293            // 293*1024 = 300032 >= NCL
#define PAD_C (NB_C*1024)
#define NB_L  196            // 196*1024 = 200704 >= NLIT
#define PAD_L (NB_L*1024)

// ---------------------------------------------------------------- utilities
__global__ void k_init_lh(const float* __restrict__ L0, float* __restrict__ Lh){
  int i = blockIdx.x*256 + threadIdx.x;            // 25,600,000 total
  Lh[i] = L0[i & 127];
}

__global__ void k_zero4(float4* __restrict__ p, int n4){
  int i = blockIdx.x*256 + threadIdx.x;
  if(i < n4) p[i] = make_float4(0.f,0.f,0.f,0.f);
}

// ---------------------------------------------------------------- CSR build
__global__ __launch_bounds__(256) void k_hist(const int* __restrict__ ci, const int* __restrict__ li,
    int* __restrict__ Pc, int* __restrict__ Pl, int ne){
  int e = blockIdx.x*256 + threadIdx.x;
  if(e < ne){ atomicAdd(&Pc[ci[e]], 1); atomicAdd(&Pl[li[e]], 1); }
}

__global__ __launch_bounds__(256) void k_scan_pass1(const int* __restrict__ P, int* __restrict__ psum){
  __shared__ int red[256];
  int t = threadIdx.x;
  int4 v = *(const int4*)&P[blockIdx.x*1024 + t*4];
  red[t] = v.x + v.y + v.z + v.w;
  __syncthreads();
  for(int ofs=128; ofs>0; ofs>>=1){
    if(t < ofs) red[t] += red[t+ofs];
    __syncthreads();
  }
  if(t == 0) psum[blockIdx.x] = red[0];
}

__global__ __launch_bounds__(512) void k_scan_pass2(int* __restrict__ psum, int nb){
  __shared__ int sA[512], sB[512];
  int t = threadIdx.x;
  sA[t] = (t < nb) ? psum[t] : 0;
  __syncthreads();
  int* src = sA; int* dst = sB;
  for(int ofs=1; ofs<512; ofs<<=1){
    int x = src[t];
    if(t >= ofs) x += src[t-ofs];
    dst[t] = x;
    __syncthreads();
    int* tmp = src; src = dst; dst = tmp;
  }
  psum[t] = t ? src[t-1] : 0;    // exclusive
}

__global__ __launch_bounds__(256) void k_scan_pass3(int* __restrict__ P, const int* __restrict__ psum){
  __shared__ int sA[256], sB[256];
  int t = threadIdx.x;
  int base = blockIdx.x*1024 + t*4;
  int4 v = *(const int4*)&P[base];
  int tsum = v.x + v.y + v.z + v.w;
  sA[t] = tsum;
  __syncthreads();
  int* src = sA; int* dst = sB;
  for(int ofs=1; ofs<256; ofs<<=1){
    int x = src[t];
    if(t >= ofs) x += src[t-ofs];
    dst[t] = x;
    __syncthreads();
    int* tmp = src; src = dst; dst = tmp;
  }
  int excl = psum[blockIdx.x] + src[t] - tsum;   // exclusive across whole array
  int4 o;
  o.x = excl;
  o.y = o.x + v.x;
  o.z = o.y + v.y;
  o.w = o.z + v.z;
  *(int4*)&P[base] = o;
}

// After k_fill, P[c] holds END offset of row c; begin(c) = c ? P[c-1] : 0.
__global__ __launch_bounds__(256) void k_fill(const int* __restrict__ ci, const int* __restrict__ li,
    int* __restrict__ Pc, int* __restrict__ Pl, int* __restrict__ clit, int* __restrict__ lcl, int ne){
  int e = blockIdx.x*256 + threadIdx.x;
  if(e < ne){
    int c = ci[e], l = li[e];
    clit[atomicAdd(&Pc[c], 1)] = l;
    lcl [atomicAdd(&Pl[l], 1)] = c;
  }
}

// ------------------- clause side: CSR gather + MLP 256->256->128 -> C (raw)
// 256 thr, 32 clauses/block. Gather: 4 waves x 8 rows, float4/lane (lanes
// 0-31 direct half, 32-63 flipped), 1-ahead index prefetch. MLP: 4x8 tile.
// Weight L2 traffic: 9375 blocks x 384 KB = 3.6 GB (was 14.4 GB at 8 rows).
__global__ __launch_bounds__(256) void k_clause_fused(
    const int* __restrict__ Pc, const int* __restrict__ clit,
    const float* __restrict__ Lh,
    const float* __restrict__ W1, const float* __restrict__ b1,
    const float* __restrict__ W2, const float* __restrict__ b2, float* __restrict__ Y){
  __shared__ float xs[32][260];
  __shared__ int rng[33];
  const int t = threadIdx.x;
  const int r0 = blockIdx.x * 32;

  if(t < 33) rng[t] = (r0 + t == 0) ? 0 : Pc[r0 + t - 1];
  __syncthreads();

  { // gather
    const int lane = t & 63, wv = t >> 6;
    const int half = lane >> 5, f4 = (lane & 31) * 4;
    for(int i=0;i<8;i++){
      int r = wv*8 + i;
      int be = rng[r], en = rng[r+1];
      float4 a = make_float4(0.f,0.f,0.f,0.f);
      int l = (be < en) ? clit[be] : 0;
      for(int e=be; e<en; e++){
        int lnext = (e+1 < en) ? clit[e+1] : 0;          // prefetch next index
        int src = half ? ((l < HALFL) ? l + HALFL : l - HALFL) : l;
        float4 v = *(const float4*)&Lh[(size_t)src*128 + f4];
        a.x += v.x; a.y += v.y; a.z += v.z; a.w += v.w;
        l = lnext;
      }
      *(float4*)&xs[r][(half<<7) + f4] = a;
    }
  }
  __syncthreads();

  const int rowg = t >> 5, colg = t & 31;
  const int rb = rowg * 4;
  float h[4][8];
  { // layer 1: 256 -> 256, 4 rows x 8 cols per thread
    const int c0 = colg * 8;
    #pragma unroll
    for(int cc=0;cc<8;cc++){
      float bv = b1[c0+cc];
      #pragma unroll
      for(int r=0;r<4;r++) h[r][cc]=bv;
    }
    for(int k=0;k<256;k+=4){
      float4 xv[4];
      #pragma unroll
      for(int r=0;r<4;r++) xv[r] = *(const float4*)&xs[rb+r][k];
      #pragma unroll
      for(int kk=0;kk<4;kk++){
        float4 wa = *(const float4*)&W1[(size_t)(k+kk)*256 + c0];
        float4 wb = *(const float4*)&W1[(size_t)(k+kk)*256 + c0 + 4];
        #pragma unroll
        for(int r=0;r<4;r++){
          float x = (kk==0)?xv[r].x:(kk==1)?xv[r].y:(kk==2)?xv[r].z:xv[r].w;
          h[r][0]=fmaf(x,wa.x,h[r][0]); h[r][1]=fmaf(x,wa.y,h[r][1]);
          h[r][2]=fmaf(x,wa.z,h[r][2]); h[r][3]=fmaf(x,wa.w,h[r][3]);
          h[r][4]=fmaf(x,wb.x,h[r][4]); h[r][5]=fmaf(x,wb.y,h[r][5]);
          h[r][6]=fmaf(x,wb.z,h[r][6]); h[r][7]=fmaf(x,wb.w,h[r][7]);
        }
      }
    }
  }
  __syncthreads();               // xs reads complete -> safe to overwrite
  { const int c0 = colg * 8;
    #pragma unroll
    for(int r=0;r<4;r++){
      *(float4*)&xs[rb+r][c0]   = make_float4(fmaxf(h[r][0],0.f),fmaxf(h[r][1],0.f),fmaxf(h[r][2],0.f),fmaxf(h[r][3],0.f));
      *(float4*)&xs[rb+r][c0+4] = make_float4(fmaxf(h[r][4],0.f),fmaxf(h[r][5],0.f),fmaxf(h[r][6],0.f),fmaxf(h[r][7],0.f));
    }
  }
  __syncthreads();

  { // layer 2: 256 -> 128, 4 rows x 4 cols per thread
    const int c2 = colg * 4;
    float4 b4 = *(const float4*)&b2[c2];
    float o[4][4];
    #pragma unroll
    for(int r=0;r<4;r++){ o[r][0]=b4.x; o[r][1]=b4.y; o[r][2]=b4.z; o[r][3]=b4.w; }
    for(int k=0;k<256;k+=4){
      float4 xv[4];
      #pragma unroll
      for(int r=0;r<4;r++) xv[r] = *(const float4*)&xs[rb+r][k];
      #pragma unroll
      for(int kk=0;kk<4;kk++){
        float4 wa = *(const float4*)&W2[(size_t)(k+kk)*128 + c2];
        #pragma unroll
        for(int r=0;r<4;r++){
          float x = (kk==0)?xv[r].x:(kk==1)?xv[r].y:(kk==2)?xv[r].z:xv[r].w;
          o[r][0]=fmaf(x,wa.x,o[r][0]); o[r][1]=fmaf(x,wa.y,o[r][1]);
          o[r][2]=fmaf(x,wa.z,o[r][2]); o[r][3]=fmaf(x,wa.w,o[r][3]);
        }
      }
    }
    #pragma unroll
    for(int r=0;r<4;r++)
      *(float4*)&Y[(size_t)(r0+rb+r)*128 + c2] = make_float4(o[r][0],o[r][1],o[r][2],o[r][3]);
  }
}

// ---------------------------------------------------------------- col stats
__global__ __launch_bounds__(256) void k_colstats(const float* __restrict__ C, float* __restrict__ st){
  const int t = threadIdx.x, col = t & 127, h = t >> 7;
  float s = 0.f, s2 = 0.f;
  for(int r = blockIdx.x*2 + h; r < NCL; r += 1024){   // grid = 512 blocks
    float v = C[(size_t)r*128 + col];
    s += v; s2 += v*v;
  }
  __shared__ float red[256];
  red[t] = s; __syncthreads();
  if(t < 128) atomicAdd(&st[col], red[t] + red[t+128]);
  __syncthreads();
  red[t] = s2; __syncthreads();
  if(t < 128) atomicAdd(&st[128+col], red[t] + red[t+128]);
}

__global__ void k_finstats(float* st){
  int j = threadIdx.x;
  if(j < 128){
    const float n = (float)NCL;
    float mean = st[j]/n;
    float var = (st[128+j] - n*mean*mean) / (n - 1.f);   // ddof=1
    var = fmaxf(var, 0.f);
    st[256+j] = mean;
    st[384+j] = 1.f/(sqrtf(var) + 1e-10f);
  }
}

// -------- literal side: gather (analytically normalized) + MLP + res + LN
// 256 thr, 32 literals/block. Gather: 4 waves x 8 rows (lanes 0-31 even row,
// 32-63 odd row of each pair), float4/lane. MLP: 4x4 tile.
__global__ __launch_bounds__(256) void k_lit_fused(
    const int* __restrict__ Pl, const int* __restrict__ lcl,
    const float* __restrict__ C, const float* __restrict__ st,
    const float* __restrict__ W1, const float* __restrict__ b1,
    const float* __restrict__ W2, const float* __restrict__ b2,
    const float* __restrict__ lng, const float* __restrict__ lnb, float* __restrict__ Lh){
  __shared__ float xs[32][132];
  __shared__ int rng[33];
  const int t = threadIdx.x;
  const int r0 = blockIdx.x * 32;

  if(t < 33) rng[t] = (r0 + t == 0) ? 0 : Pl[r0 + t - 1];
  __syncthreads();

  { const int lane = t & 63, wv = t >> 6;
    const int half = lane >> 5, f4 = (lane & 31) * 4;
    float4 mean4 = *(const float4*)&st[256+f4];
    float4 isd4  = *(const float4*)&st[384+f4];
    for(int i=0;i<4;i++){
      int r = wv*8 + i*2 + half;
      int be = rng[r], en = rng[r+1];
      float4 a = make_float4(0.f,0.f,0.f,0.f);
      int c = (be < en) ? lcl[be] : 0;
      for(int e=be; e<en; e++){
        int cnext = (e+1 < en) ? lcl[e+1] : 0;
        float4 v = *(const float4*)&C[(size_t)c*128 + f4];
        a.x += v.x; a.y += v.y; a.z += v.z; a.w += v.w;
        c = cnext;
      }
      float dg = (float)(en - be);
      a.x = (a.x - dg*mean4.x)*isd4.x; a.y = (a.y - dg*mean4.y)*isd4.y;
      a.z = (a.z - dg*mean4.z)*isd4.z; a.w = (a.w - dg*mean4.w)*isd4.w;
      *(float4*)&xs[r][f4] = a;
    }
  }
  __syncthreads();

  const int rowg = t >> 5, colg = t & 31;
  const int rb = rowg * 4, c0 = colg * 4;
  float h[4][4];
  { // layer 1: 128 -> 128, 4 rows x 4 cols
    float4 b4 = *(const float4*)&b1[c0];
    #pragma unroll
    for(int r=0;r<4;r++){ h[r][0]=b4.x; h[r][1]=b4.y; h[r][2]=b4.z; h[r][3]=b4.w; }
    for(int k=0;k<128;k+=4){
      float4 xv[4];
      #pragma unroll
      for(int r=0;r<4;r++) xv[r] = *(const float4*)&xs[rb+r][k];
      #pragma unroll
      for(int kk=0;kk<4;kk++){
        float4 wa = *(const float4*)&W1[(size_t)(k+kk)*128 + c0];
        #pragma unroll
        for(int r=0;r<4;r++){
          float x = (kk==0)?xv[r].x:(kk==1)?xv[r].y:(kk==2)?xv[r].z:xv[r].w;
          h[r][0]=fmaf(x,wa.x,h[r][0]); h[r][1]=fmaf(x,wa.y,h[r][1]);
          h[r][2]=fmaf(x,wa.z,h[r][2]); h[r][3]=fmaf(x,wa.w,h[r][3]);
        }
      }
    }
  }
  __syncthreads();
  #pragma unroll
  for(int r=0;r<4;r++)
    *(float4*)&xs[rb+r][c0] = make_float4(fmaxf(h[r][0],0.f),fmaxf(h[r][1],0.f),fmaxf(h[r][2],0.f),fmaxf(h[r][3],0.f));
  __syncthreads();

  float y[4][4];
  { // layer 2: 128 -> 128
    float4 b4 = *(const float4*)&b2[c0];
    #pragma unroll
    for(int r=0;r<4;r++){ y[r][0]=b4.x; y[r][1]=b4.y; y[r][2]=b4.z; y[r][3]=b4.w; }
    for(int k=0;k<128;k+=4){
      float4 xv[4];
      #pragma unroll
      for(int r=0;r<4;r++) xv[r] = *(const float4*)&xs[rb+r][k];
      #pragma unroll
      for(int kk=0;kk<4;kk++){
        float4 wa = *(const float4*)&W2[(size_t)(k+kk)*128 + c0];
        #pragma unroll
        for(int r=0;r<4;r++){
          float x = (kk==0)?xv[r].x:(kk==1)?xv[r].y:(kk==2)?xv[r].z:xv[r].w;
          y[r][0]=fmaf(x,wa.x,y[r][0]); y[r][1]=fmaf(x,wa.y,y[r][1]);
          y[r][2]=fmaf(x,wa.z,y[r][2]); y[r][3]=fmaf(x,wa.w,y[r][3]);
        }
      }
    }
  }

  { // + 0.1*residual, LayerNorm over 128 (32 colg lanes x 4 cols)
    float4 gv = *(const float4*)&lng[c0];
    float4 bv = *(const float4*)&lnb[c0];
    #pragma unroll
    for(int r=0;r<4;r++){
      size_t row = (size_t)(r0 + rb + r);
      float4 la = *(const float4*)&Lh[row*128 + c0];
      y[r][0] += 0.1f*la.x; y[r][1] += 0.1f*la.y; y[r][2] += 0.1f*la.z; y[r][3] += 0.1f*la.w;
      float s = 0.f, s2 = 0.f;
      #pragma unroll
      for(int cc=0;cc<4;cc++){ s += y[r][cc]; s2 += y[r][cc]*y[r][cc]; }
      #pragma unroll
      for(int m=1;m<32;m<<=1){ s += __shfl_xor(s,m,64); s2 += __shfl_xor(s2,m,64); }
      float mean = s*(1.f/128.f);
      float var  = s2*(1.f/128.f) - mean*mean;
      float rs   = rsqrtf(fmaxf(var, 0.f) + 1e-5f);
      *(float4*)&Lh[row*128 + c0] = make_float4(
        (y[r][0]-mean)*rs*gv.x + bv.x, (y[r][1]-mean)*rs*gv.y + bv.y,
        (y[r][2]-mean)*rs*gv.z + bv.z, (y[r][3]-mean)*rs*gv.w + bv.w);
    }
  }
}

// ---------------------------------------------------------------- heads
// 256 thr, 32 vars/block, 4x8 tile.
__global__ __launch_bounds__(256) void k_head_v(const float* __restrict__ Lh,
    const float* __restrict__ W1d, const float* __restrict__ b1d, const float* __restrict__ W2d, const float* __restrict__ b2d,
    const float* __restrict__ W1c, const float* __restrict__ b1c, const float* __restrict__ W2c, const float* __restrict__ b2c,
    float* __restrict__ out){
  __shared__ float xs[32][260];
  const int t = threadIdx.x;
  const int v0 = blockIdx.x * 32;
  { const int lane = t & 63, wv = t >> 6;
    const int half = lane >> 5, f4 = (lane & 31) * 4;
    #pragma unroll
    for(int i=0;i<8;i++){
      int r = wv*8 + i;
      *(float4*)&xs[r][(half<<7)+f4] =
        *(const float4*)&Lh[(size_t)(v0 + r + (half ? HALFL : 0))*128 + f4];
    }
  }
  __syncthreads();
  const int rowg = t >> 5, colg = t & 31;
  const int rb = rowg*4, c0 = colg*8;
  for(int hd=0; hd<2; hd++){
    const float* W1 = hd ? W1c : W1d;
    const float* b1 = hd ? b1c : b1d;
    const float* W2 = hd ? W2c : W2d;
    const float* b2 = hd ? b2c : b2d;
    float h[4][8];
    #pragma unroll
    for(int cc=0;cc<8;cc++){
      float bv = b1[c0+cc];
      #pragma unroll
      for(int r=0;r<4;r++) h[r][cc]=bv;
    }
    for(int k=0;k<256;k+=4){
      float4 xv[4];
      #pragma unroll
      for(int r=0;r<4;r++) xv[r] = *(const float4*)&xs[rb+r][k];
      #pragma unroll
      for(int kk=0;kk<4;kk++){
        float4 wa = *(const float4*)&W1[(size_t)(k+kk)*256 + c0];
        float4 wb = *(const float4*)&W1[(size_t)(k+kk)*256 + c0 + 4];
        #pragma unroll
        for(int r=0;r<4;r++){
          float x = (kk==0)?xv[r].x:(kk==1)?xv[r].y:(kk==2)?xv[r].z:xv[r].w;
          h[r][0]=fmaf(x,wa.x,h[r][0]); h[r][1]=fmaf(x,wa.y,h[r][1]);
          h[r][2]=fmaf(x,wa.z,h[r][2]); h[r][3]=fmaf(x,wa.w,h[r][3]);
          h[r][4]=fmaf(x,wb.x,h[r][4]); h[r][5]=fmaf(x,wb.y,h[r][5]);
          h[r][6]=fmaf(x,wb.z,h[r][6]); h[r][7]=fmaf(x,wb.w,h[r][7]);
        }
      }
    }
    float4 w2a = *(const float4*)&W2[c0];
    float4 w2b = *(const float4*)&W2[c0+4];
    #pragma unroll
    for(int r=0;r<4;r++){
      float p = fmaxf(h[r][0],0.f)*w2a.x + fmaxf(h[r][1],0.f)*w2a.y
              + fmaxf(h[r][2],0.f)*w2a.z + fmaxf(h[r][3],0.f)*w2a.w
              + fmaxf(h[r][4],0.f)*w2b.x + fmaxf(h[r][5],0.f)*w2b.y
              + fmaxf(h[r][6],0.f)*w2b.z + fmaxf(h[r][7],0.f)*w2b.w;
      #pragma unroll
      for(int m=1;m<32;m<<=1) p += __shfl_xor(p,m,64);
      if(colg == 0) out[(size_t)hd*NVAR + v0 + rb + r] = p + b2[0];
    }
  }
}

// 256 thr, 32 clauses/block, 4x4 tile; normalizes C on load.
__global__ __launch_bounds__(256) void k_head_c(const float* __restrict__ C,
    const float* __restrict__ st,
    const float* __restrict__ W1, const float* __restrict__ b1,
    const float* __restrict__ W2, const float* __restrict__ b2,
    float* __restrict__ out){
  __shared__ float xs[32][132];
  const int t = threadIdx.x;
  const int cb = blockIdx.x * 32;
  { const int rg = t >> 5, f4 = (t & 31) * 4;
    float4 mean4 = *(const float4*)&st[256+f4];
    float4 isd4  = *(const float4*)&st[384+f4];
    #pragma unroll
    for(int i=0;i<4;i++){
      int r = rg + i*8;
      float4 v = *(const float4*)&C[(size_t)(cb+r)*128 + f4];
      xs[r][f4]   = (v.x - mean4.x)*isd4.x;
      xs[r][f4+1] = (v.y - mean4.y)*isd4.y;
      xs[r][f4+2] = (v.z - mean4.z)*isd4.z;
      xs[r][f4+3] = (v.w - mean4.w)*isd4.w;
    }
  }
  __syncthreads();
  const int rowg = t >> 5, colg = t & 31;
  const int rb = rowg*4, c2 = colg*4;
  float h[4][4];
  float4 b4 = *(const float4*)&b1[c2];
  #pragma unroll
  for(int r=0;r<4;r++){ h[r][0]=b4.x; h[r][1]=b4.y; h[r][2]=b4.z; h[r][3]=b4.w; }
  for(int k=0;k<128;k+=4){
    float4 xv[4];
    #pragma unroll
    for(int r=0;r<4;r++) xv[r] = *(const float4*)&xs[rb+r][k];
    #pragma unroll
    for(int kk=0;kk<4;kk++){
      float4 wa = *(const float4*)&W1[(size_t)(k+kk)*128 + c2];
      #pragma unroll
      for(int r=0;r<4;r++){
        float x = (kk==0)?xv[r].x:(kk==1)?xv[r].y:(kk==2)?xv[r].z:xv[r].w;
        h[r][0]=fmaf(x,wa.x,h[r][0]); h[r][1]=fmaf(x,wa.y,h[r][1]);
        h[r][2]=fmaf(x,wa.z,h[r][2]); h[r][3]=fmaf(x,wa.w,h[r][3]);
      }
    }
  }
  float4 w2 = *(const float4*)&W2[c2];
  #pragma unroll
  for(int r=0;r<4;r++){
    float p = fmaxf(h[r][0],0.f)*w2.x + fmaxf(h[r][1],0.f)*w2.y
            + fmaxf(h[r][2],0.f)*w2.z + fmaxf(h[r][3],0.f)*w2.w;
    #pragma unroll
    for(int m=1;m<32;m<<=1) p += __shfl_xor(p,m,64);
    if(colg == 0) out[cb + rb + r] = p + b2[0];
  }
}

// ---------------------------------------------------------------- launch
extern "C" void kernel_launch(void* const* d_in, const int* in_sizes, int n_in,
                              void* d_out, int out_size, void* d_ws, size_t ws_size,
                              hipStream_t stream){
  const float* L0   = (const float*)d_in[0];
  const float* lng  = (const float*)d_in[1];
  const float* lnb  = (const float*)d_in[2];
  const float* CuW1 = (const float*)d_in[3];
  const float* Cub1 = (const float*)d_in[4];
  const float* CuW2 = (const float*)d_in[5];
  const float* Cub2 = (const float*)d_in[6];
  const float* LuW1 = (const float*)d_in[7];
  const float* Lub1 = (const float*)d_in[8];
  const float* LuW2 = (const float*)d_in[9];
  const float* Lub2 = (const float*)d_in[10];
  const float* VdW1 = (const float*)d_in[11];
  const float* Vdb1 = (const float*)d_in[12];
  const float* VdW2 = (const float*)d_in[13];
  const float* Vdb2 = (const float*)d_in[14];
  const float* VcW1 = (const float*)d_in[15];
  const float* Vcb1 = (const float*)d_in[16];
  const float* VcW2 = (const float*)d_in[17];
  const float* Vcb2 = (const float*)d_in[18];
  const float* CsW1 = (const float*)d_in[19];
  const float* Csb1 = (const float*)d_in[20];
  const float* CsW2 = (const float*)d_in[21];
  const float* Csb2 = (const float*)d_in[22];
  const int* cidx = (const int*)d_in[23];
  const int* lidx = (const int*)d_in[24];
  const int  ne   = in_sizes[23];

  float* ws   = (float*)d_ws;
  float* Lh   = ws;                        // 25,600,000 f32
  float* C    = ws + 25600000;             // 38,400,000 f32 -> end 64,000,000
  float* st   = ws + 64000000;             // 512: sum|sumsq|mean|isd
  int*   ib   = (int*)(ws + 64000512);     // int region
  int*   Pc   = ib;                        // PAD_C = 300,032
  int*   Pl   = ib + PAD_C;                // PAD_L = 200,704
  int*   clit = ib + PAD_C + PAD_L;        // 1,000,000
  int*   lcl  = clit + 1000000;            // 1,000,000
  int*   psum = lcl + 1000000;             // 512
  // total ws ~= 266 MB
  float* out = (float*)d_out;              // fp32: drat|core|c_core

  k_init_lh<<<100000, 256, 0, stream>>>(L0, Lh);

  // CSR build (counting sort both directions)
  k_zero4<<<489, 256, 0, stream>>>((float4*)Pc, (PAD_C + PAD_L)/4);
  k_hist<<<(ne+255)/256, 256, 0, stream>>>(cidx, lidx, Pc, Pl, ne);
  k_scan_pass1<<<NB_C, 256, 0, stream>>>(Pc, psum);
  k_scan_pass2<<<1, 512, 0, stream>>>(psum, NB_C);
  k_scan_pass3<<<NB_C, 256, 0, stream>>>(Pc, psum);
  k_scan_pass1<<<NB_L, 256, 0, stream>>>(Pl, psum);
  k_scan_pass2<<<1, 512, 0, stream>>>(psum, NB_L);
  k_scan_pass3<<<NB_L, 256, 0, stream>>>(Pl, psum);
  k_fill<<<(ne+255)/256, 256, 0, stream>>>(cidx, lidx, Pc, Pl, clit, lcl, ne);

  for(int hop=0; hop<4; hop++){
    k_zero4<<<1, 256, 0, stream>>>((float4*)st, 128);
    k_clause_fused<<<9375, 256, 0, stream>>>(Pc, clit, Lh, CuW1, Cub1, CuW2, Cub2, C);
    k_colstats<<<512, 256, 0, stream>>>(C, st);
    k_finstats<<<1, 128, 0, stream>>>(st);
    k_lit_fused<<<6250, 256, 0, stream>>>(Pl, lcl, C, st, LuW1, Lub1, LuW2, Lub2, lng, lnb, Lh);
  }
  k_head_v<<<3125, 256, 0, stream>>>(Lh, VdW1, Vdb1, VdW2, Vdb2, VcW1, Vcb1, VcW2, Vcb2, out);
  k_head_c<<<9375, 256, 0, stream>>>(C, st, CsW1, Csb1, CsW2, Csb2, out + 200000);
}

// Round 10
// 9167.386 us; speedup vs baseline: 1.0568x; 1.0568x over previous
//
#include <hip/hip_runtime.h>
#include <hip/hip_bf16.h>

#define NCL   300000
#define NLIT  200000
#define HALFL 100000
#define NVAR  100000

#define NB_C  293            // 293*1024 = 300032 >= NCL
#define PAD_C (NB_C*1024)
#define NB_L  196            // 196*1024 = 200704 >= NLIT
#define PAD_L (NB_L*1024)

// ---------------------------------------------------------------- utilities
__global__ void k_init_lh(const float* __restrict__ L0, float* __restrict__ Lh){
  int i = blockIdx.x*256 + threadIdx.x;            // 25,600,000 total
  Lh[i] = L0[i & 127];
}

__global__ void k_zero4(float4* __restrict__ p, int n4){
  int i = blockIdx.x*256 + threadIdx.x;
  if(i < n4) p[i] = make_float4(0.f,0.f,0.f,0.f);
}

// ---------------------------------------------------------------- CSR build
__global__ __launch_bounds__(256) void k_hist(const int* __restrict__ ci, const int* __restrict__ li,
    int* __restrict__ Pc, int* __restrict__ Pl, int ne){
  int e = blockIdx.x*256 + threadIdx.x;
  if(e < ne){ atomicAdd(&Pc[ci[e]], 1); atomicAdd(&Pl[li[e]], 1); }
}

__global__ __launch_bounds__(256) void k_scan_pass1(const int* __restrict__ P, int* __restrict__ psum){
  __shared__ int red[256];
  int t = threadIdx.x;
  int4 v = *(const int4*)&P[blockIdx.x*1024 + t*4];
  red[t] = v.x + v.y + v.z + v.w;
  __syncthreads();
  for(int ofs=128; ofs>0; ofs>>=1){
    if(t < ofs) red[t] += red[t+ofs];
    __syncthreads();
  }
  if(t == 0) psum[blockIdx.x] = red[0];
}

__global__ __launch_bounds__(512) void k_scan_pass2(int* __restrict__ psum, int nb){
  __shared__ int sA[512], sB[512];
  int t = threadIdx.x;
  sA[t] = (t < nb) ? psum[t] : 0;
  __syncthreads();
  int* src = sA; int* dst = sB;
  for(int ofs=1; ofs<512; ofs<<=1){
    int x = src[t];
    if(t >= ofs) x += src[t-ofs];
    dst[t] = x;
    __syncthreads();
    int* tmp = src; src = dst; dst = tmp;
  }
  psum[t] = t ? src[t-1] : 0;    // exclusive
}

__global__ __launch_bounds__(256) void k_scan_pass3(int* __restrict__ P, const int* __restrict__ psum){
  __shared__ int sA[256], sB[256];
  int t = threadIdx.x;
  int base = blockIdx.x*1024 + t*4;
  int4 v = *(const int4*)&P[base];
  int tsum = v.x + v.y + v.z + v.w;
  sA[t] = tsum;
  __syncthreads();
  int* src = sA; int* dst = sB;
  for(int ofs=1; ofs<256; ofs<<=1){
    int x = src[t];
    if(t >= ofs) x += src[t-ofs];
    dst[t] = x;
    __syncthreads();
    int* tmp = src; src = dst; dst = tmp;
  }
  int excl = psum[blockIdx.x] + src[t] - tsum;   // exclusive across whole array
  int4 o;
  o.x = excl;
  o.y = o.x + v.x;
  o.z = o.y + v.y;
  o.w = o.z + v.z;
  *(int4*)&P[base] = o;
}

// After k_fill, P[c] holds END offset of row c; begin(c) = c ? P[c-1] : 0.
__global__ __launch_bounds__(256) void k_fill(const int* __restrict__ ci, const int* __restrict__ li,
    int* __restrict__ Pc, int* __restrict__ Pl, int* __restrict__ clit, int* __restrict__ lcl, int ne){
  int e = blockIdx.x*256 + threadIdx.x;
  if(e < ne){
    int c = ci[e], l = li[e];
    clit[atomicAdd(&Pc[c], 1)] = l;
    lcl [atomicAdd(&Pl[l], 1)] = c;
  }
}

// ------------------- clause side: CSR gather + MLP 256->256->128 -> C (raw)
// 256 thr, 16 clauses/block. LDS 16.7 KB -> 8 blocks/CU = 32 waves = 100% occ.
// Gather: 4 waves x 4 rows, float4/lane (lanes 0-31 direct, 32-63 flipped),
// 1-ahead index prefetch. MLP: 2 rows x 8 cols per thread.
__global__ __launch_bounds__(256) void k_clause_fused(
    const int* __restrict__ Pc, const int* __restrict__ clit,
    const float* __restrict__ Lh,
    const float* __restrict__ W1, const float* __restrict__ b1,
    const float* __restrict__ W2, const float* __restrict__ b2, float* __restrict__ Y){
  __shared__ float xs[16][260];
  __shared__ int rng[17];
  const int t = threadIdx.x;
  const int r0 = blockIdx.x * 16;

  if(t < 17) rng[t] = (r0 + t == 0) ? 0 : Pc[r0 + t - 1];
  __syncthreads();

  { // gather
    const int lane = t & 63, wv = t >> 6;
    const int half = lane >> 5, f4 = (lane & 31) * 4;
    for(int i=0;i<4;i++){
      int r = wv*4 + i;
      int be = rng[r], en = rng[r+1];
      float4 a = make_float4(0.f,0.f,0.f,0.f);
      int l = (be < en) ? clit[be] : 0;
      for(int e=be; e<en; e++){
        int lnext = (e+1 < en) ? clit[e+1] : 0;          // prefetch next index
        int src = half ? ((l < HALFL) ? l + HALFL : l - HALFL) : l;
        float4 v = *(const float4*)&Lh[(size_t)src*128 + f4];
        a.x += v.x; a.y += v.y; a.z += v.z; a.w += v.w;
        l = lnext;
      }
      *(float4*)&xs[r][(half<<7) + f4] = a;
    }
  }
  __syncthreads();

  const int rowg = t >> 5, colg = t & 31;
  const int rb = rowg * 2;
  float h[2][8];
  { // layer 1: 256 -> 256, 2 rows x 8 cols per thread
    const int c0 = colg * 8;
    #pragma unroll
    for(int cc=0;cc<8;cc++){ float bv = b1[c0+cc]; h[0][cc]=bv; h[1][cc]=bv; }
    for(int k=0;k<256;k+=4){
      float4 xv[2];
      #pragma unroll
      for(int r=0;r<2;r++) xv[r] = *(const float4*)&xs[rb+r][k];
      #pragma unroll
      for(int kk=0;kk<4;kk++){
        float4 wa = *(const float4*)&W1[(size_t)(k+kk)*256 + c0];
        float4 wb = *(const float4*)&W1[(size_t)(k+kk)*256 + c0 + 4];
        #pragma unroll
        for(int r=0;r<2;r++){
          float x = (kk==0)?xv[r].x:(kk==1)?xv[r].y:(kk==2)?xv[r].z:xv[r].w;
          h[r][0]=fmaf(x,wa.x,h[r][0]); h[r][1]=fmaf(x,wa.y,h[r][1]);
          h[r][2]=fmaf(x,wa.z,h[r][2]); h[r][3]=fmaf(x,wa.w,h[r][3]);
          h[r][4]=fmaf(x,wb.x,h[r][4]); h[r][5]=fmaf(x,wb.y,h[r][5]);
          h[r][6]=fmaf(x,wb.z,h[r][6]); h[r][7]=fmaf(x,wb.w,h[r][7]);
        }
      }
    }
  }
  __syncthreads();               // xs reads complete -> safe to overwrite
  { const int c0 = colg * 8;
    #pragma unroll
    for(int r=0;r<2;r++){
      *(float4*)&xs[rb+r][c0]   = make_float4(fmaxf(h[r][0],0.f),fmaxf(h[r][1],0.f),fmaxf(h[r][2],0.f),fmaxf(h[r][3],0.f));
      *(float4*)&xs[rb+r][c0+4] = make_float4(fmaxf(h[r][4],0.f),fmaxf(h[r][5],0.f),fmaxf(h[r][6],0.f),fmaxf(h[r][7],0.f));
    }
  }
  __syncthreads();

  { // layer 2: 256 -> 128, 2 rows x 4 cols per thread
    const int c2 = colg * 4;
    float4 b4 = *(const float4*)&b2[c2];
    float o[2][4];
    #pragma unroll
    for(int r=0;r<2;r++){ o[r][0]=b4.x; o[r][1]=b4.y; o[r][2]=b4.z; o[r][3]=b4.w; }
    for(int k=0;k<256;k+=4){
      float4 xv[2];
      #pragma unroll
      for(int r=0;r<2;r++) xv[r] = *(const float4*)&xs[rb+r][k];
      #pragma unroll
      for(int kk=0;kk<4;kk++){
        float4 wa = *(const float4*)&W2[(size_t)(k+kk)*128 + c2];
        #pragma unroll
        for(int r=0;r<2;r++){
          float x = (kk==0)?xv[r].x:(kk==1)?xv[r].y:(kk==2)?xv[r].z:xv[r].w;
          o[r][0]=fmaf(x,wa.x,o[r][0]); o[r][1]=fmaf(x,wa.y,o[r][1]);
          o[r][2]=fmaf(x,wa.z,o[r][2]); o[r][3]=fmaf(x,wa.w,o[r][3]);
        }
      }
    }
    #pragma unroll
    for(int r=0;r<2;r++)
      *(float4*)&Y[(size_t)(r0+rb+r)*128 + c2] = make_float4(o[r][0],o[r][1],o[r][2],o[r][3]);
  }
}

// ---------------------------------------------------------------- col stats
__global__ __launch_bounds__(256) void k_colstats(const float* __restrict__ C, float* __restrict__ st){
  const int t = threadIdx.x, col = t & 127, h = t >> 7;
  float s = 0.f, s2 = 0.f;
  for(int r = blockIdx.x*2 + h; r < NCL; r += 1024){   // grid = 512 blocks
    float v = C[(size_t)r*128 + col];
    s += v; s2 += v*v;
  }
  __shared__ float red[256];
  red[t] = s; __syncthreads();
  if(t < 128) atomicAdd(&st[col], red[t] + red[t+128]);
  __syncthreads();
  red[t] = s2; __syncthreads();
  if(t < 128) atomicAdd(&st[128+col], red[t] + red[t+128]);
}

__global__ void k_finstats(float* st){
  int j = threadIdx.x;
  if(j < 128){
    const float n = (float)NCL;
    float mean = st[j]/n;
    float var = (st[128+j] - n*mean*mean) / (n - 1.f);   // ddof=1
    var = fmaxf(var, 0.f);
    st[256+j] = mean;
    st[384+j] = 1.f/(sqrtf(var) + 1e-10f);
  }
}

// -------- literal side: gather (analytically normalized) + MLP + res + LN
// 256 thr, 32 literals/block, LDS 16.9 KB -> 100% occ. 4x4 tile.
__global__ __launch_bounds__(256) void k_lit_fused(
    const int* __restrict__ Pl, const int* __restrict__ lcl,
    const float* __restrict__ C, const float* __restrict__ st,
    const float* __restrict__ W1, const float* __restrict__ b1,
    const float* __restrict__ W2, const float* __restrict__ b2,
    const float* __restrict__ lng, const float* __restrict__ lnb, float* __restrict__ Lh){
  __shared__ float xs[32][132];
  __shared__ int rng[33];
  const int t = threadIdx.x;
  const int r0 = blockIdx.x * 32;

  if(t < 33) rng[t] = (r0 + t == 0) ? 0 : Pl[r0 + t - 1];
  __syncthreads();

  { const int lane = t & 63, wv = t >> 6;
    const int half = lane >> 5, f4 = (lane & 31) * 4;
    float4 mean4 = *(const float4*)&st[256+f4];
    float4 isd4  = *(const float4*)&st[384+f4];
    for(int i=0;i<4;i++){
      int r = wv*8 + i*2 + half;
      int be = rng[r], en = rng[r+1];
      float4 a = make_float4(0.f,0.f,0.f,0.f);
      int c = (be < en) ? lcl[be] : 0;
      for(int e=be; e<en; e++){
        int cnext = (e+1 < en) ? lcl[e+1] : 0;
        float4 v = *(const float4*)&C[(size_t)c*128 + f4];
        a.x += v.x; a.y += v.y; a.z += v.z; a.w += v.w;
        c = cnext;
      }
      float dg = (float)(en - be);
      a.x = (a.x - dg*mean4.x)*isd4.x; a.y = (a.y - dg*mean4.y)*isd4.y;
      a.z = (a.z - dg*mean4.z)*isd4.z; a.w = (a.w - dg*mean4.w)*isd4.w;
      *(float4*)&xs[r][f4] = a;
    }
  }
  __syncthreads();

  const int rowg = t >> 5, colg = t & 31;
  const int rb = rowg * 4, c0 = colg * 4;
  float h[4][4];
  { // layer 1: 128 -> 128, 4 rows x 4 cols
    float4 b4 = *(const float4*)&b1[c0];
    #pragma unroll
    for(int r=0;r<4;r++){ h[r][0]=b4.x; h[r][1]=b4.y; h[r][2]=b4.z; h[r][3]=b4.w; }
    for(int k=0;k<128;k+=4){
      float4 xv[4];
      #pragma unroll
      for(int r=0;r<4;r++) xv[r] = *(const float4*)&xs[rb+r][k];
      #pragma unroll
      for(int kk=0;kk<4;kk++){
        float4 wa = *(const float4*)&W1[(size_t)(k+kk)*128 + c0];
        #pragma unroll
        for(int r=0;r<4;r++){
          float x = (kk==0)?xv[r].x:(kk==1)?xv[r].y:(kk==2)?xv[r].z:xv[r].w;
          h[r][0]=fmaf(x,wa.x,h[r][0]); h[r][1]=fmaf(x,wa.y,h[r][1]);
          h[r][2]=fmaf(x,wa.z,h[r][2]); h[r][3]=fmaf(x,wa.w,h[r][3]);
        }
      }
    }
  }
  __syncthreads();
  #pragma unroll
  for(int r=0;r<4;r++)
    *(float4*)&xs[rb+r][c0] = make_float4(fmaxf(h[r][0],0.f),fmaxf(h[r][1],0.f),fmaxf(h[r][2],0.f),fmaxf(h[r][3],0.f));
  __syncthreads();

  float y[4][4];
  { // layer 2: 128 -> 128
    float4 b4 = *(const float4*)&b2[c0];
    #pragma unroll
    for(int r=0;r<4;r++){ y[r][0]=b4.x; y[r][1]=b4.y; y[r][2]=b4.z; y[r][3]=b4.w; }
    for(int k=0;k<128;k+=4){
      float4 xv[4];
      #pragma unroll
      for(int r=0;r<4;r++) xv[r] = *(const float4*)&xs[rb+r][k];
      #pragma unroll
      for(int kk=0;kk<4;kk++){
        float4 wa = *(const float4*)&W2[(size_t)(k+kk)*128 + c0];
        #pragma unroll
        for(int r=0;r<4;r++){
          float x = (kk==0)?xv[r].x:(kk==1)?xv[r].y:(kk==2)?xv[r].z:xv[r].w;
          y[r][0]=fmaf(x,wa.x,y[r][0]); y[r][1]=fmaf(x,wa.y,y[r][1]);
          y[r][2]=fmaf(x,wa.z,y[r][2]); y[r][3]=fmaf(x,wa.w,y[r][3]);
        }
      }
    }
  }

  { // + 0.1*residual, LayerNorm over 128 (32 colg lanes x 4 cols)
    float4 gv = *(const float4*)&lng[c0];
    float4 bv = *(const float4*)&lnb[c0];
    #pragma unroll
    for(int r=0;r<4;r++){
      size_t row = (size_t)(r0 + rb + r);
      float4 la = *(const float4*)&Lh[row*128 + c0];
      y[r][0] += 0.1f*la.x; y[r][1] += 0.1f*la.y; y[r][2] += 0.1f*la.z; y[r][3] += 0.1f*la.w;
      float s = 0.f, s2 = 0.f;
      #pragma unroll
      for(int cc=0;cc<4;cc++){ s += y[r][cc]; s2 += y[r][cc]*y[r][cc]; }
      #pragma unroll
      for(int m=1;m<32;m<<=1){ s += __shfl_xor(s,m,64); s2 += __shfl_xor(s2,m,64); }
      float mean = s*(1.f/128.f);
      float var  = s2*(1.f/128.f) - mean*mean;
      float rs   = rsqrtf(fmaxf(var, 0.f) + 1e-5f);
      *(float4*)&Lh[row*128 + c0] = make_float4(
        (y[r][0]-mean)*rs*gv.x + bv.x, (y[r][1]-mean)*rs*gv.y + bv.y,
        (y[r][2]-mean)*rs*gv.z + bv.z, (y[r][3]-mean)*rs*gv.w + bv.w);
    }
  }
}

// ---------------------------------------------------------------- heads
// 256 thr, 16 vars/block, 2x8 tile. LDS 16.7 KB -> 100% occ.
__global__ __launch_bounds__(256) void k_head_v(const float* __restrict__ Lh,
    const float* __restrict__ W1d, const float* __restrict__ b1d, const float* __restrict__ W2d, const float* __restrict__ b2d,
    const float* __restrict__ W1c, const float* __restrict__ b1c, const float* __restrict__ W2c, const float* __restrict__ b2c,
    float* __restrict__ out){
  __shared__ float xs[16][260];
  const int t = threadIdx.x;
  const int v0 = blockIdx.x * 16;
  { const int lane = t & 63, wv = t >> 6;
    const int half = lane >> 5, f4 = (lane & 31) * 4;
    #pragma unroll
    for(int i=0;i<4;i++){
      int r = wv*4 + i;
      *(float4*)&xs[r][(half<<7)+f4] =
        *(const float4*)&Lh[(size_t)(v0 + r + (half ? HALFL : 0))*128 + f4];
    }
  }
  __syncthreads();
  const int rowg = t >> 5, colg = t & 31;
  const int rb = rowg*2, c0 = colg*8;
  for(int hd=0; hd<2; hd++){
    const float* W1 = hd ? W1c : W1d;
    const float* b1 = hd ? b1c : b1d;
    const float* W2 = hd ? W2c : W2d;
    const float* b2 = hd ? b2c : b2d;
    float h[2][8];
    #pragma unroll
    for(int cc=0;cc<8;cc++){ float bv = b1[c0+cc]; h[0][cc]=bv; h[1][cc]=bv; }
    for(int k=0;k<256;k+=4){
      float4 xv[2];
      #pragma unroll
      for(int r=0;r<2;r++) xv[r] = *(const float4*)&xs[rb+r][k];
      #pragma unroll
      for(int kk=0;kk<4;kk++){
        float4 wa = *(const float4*)&W1[(size_t)(k+kk)*256 + c0];
        float4 wb = *(const float4*)&W1[(size_t)(k+kk)*256 + c0 + 4];
        #pragma unroll
        for(int r=0;r<2;r++){
          float x = (kk==0)?xv[r].x:(kk==1)?xv[r].y:(kk==2)?xv[r].z:xv[r].w;
          h[r][0]=fmaf(x,wa.x,h[r][0]); h[r][1]=fmaf(x,wa.y,h[r][1]);
          h[r][2]=fmaf(x,wa.z,h[r][2]); h[r][3]=fmaf(x,wa.w,h[r][3]);
          h[r][4]=fmaf(x,wb.x,h[r][4]); h[r][5]=fmaf(x,wb.y,h[r][5]);
          h[r][6]=fmaf(x,wb.z,h[r][6]); h[r][7]=fmaf(x,wb.w,h[r][7]);
        }
      }
    }
    float4 w2a = *(const float4*)&W2[c0];
    float4 w2b = *(const float4*)&W2[c0+4];
    #pragma unroll
    for(int r=0;r<2;r++){
      float p = fmaxf(h[r][0],0.f)*w2a.x + fmaxf(h[r][1],0.f)*w2a.y
              + fmaxf(h[r][2],0.f)*w2a.z + fmaxf(h[r][3],0.f)*w2a.w
              + fmaxf(h[r][4],0.f)*w2b.x + fmaxf(h[r][5],0.f)*w2b.y
              + fmaxf(h[r][6],0.f)*w2b.z + fmaxf(h[r][7],0.f)*w2b.w;
      #pragma unroll
      for(int m=1;m<32;m<<=1) p += __shfl_xor(p,m,64);
      if(colg == 0) out[(size_t)hd*NVAR + v0 + rb + r] = p + b2[0];
    }
  }
}

// 64 thr, 8 clauses/block; normalizes C on load. (R8-proven version.)
__global__ __launch_bounds__(64) void k_head_c(const float* __restrict__ C,
    const float* __restrict__ st,
    const float* __restrict__ W1, const float* __restrict__ b1,
    const float* __restrict__ W2, const float* __restrict__ b2,
    float* __restrict__ out){
  __shared__ float xs[8][128];
  const int t = threadIdx.x;
  const size_t c0 = (size_t)blockIdx.x * 8;
  { float m0 = st[256+t], m1 = st[256+t+64];
    float i0 = st[384+t], i1 = st[384+t+64];
    #pragma unroll
    for(int r=0;r<8;r++){
      xs[r][t]    = (C[(c0+r)*128 + t]      - m0) * i0;
      xs[r][t+64] = (C[(c0+r)*128 + t + 64] - m1) * i1;
    }
  }
  __syncthreads();
  float a0[8], a1[8];
  float bv0 = b1[t], bv1 = b1[t+64];
  #pragma unroll
  for(int r=0;r<8;r++){ a0[r]=bv0; a1[r]=bv1; }
  for(int k=0;k<128;k+=4){
    float w0[4], w1[4];
    #pragma unroll
    for(int kk=0;kk<4;kk++){ w0[kk]=W1[(size_t)(k+kk)*128 + t]; w1[kk]=W1[(size_t)(k+kk)*128 + t + 64]; }
    #pragma unroll
    for(int r=0;r<8;r++){
      float4 tv = *(const float4*)&xs[r][k];
      a0[r] += tv.x*w0[0]+tv.y*w0[1]+tv.z*w0[2]+tv.w*w0[3];
      a1[r] += tv.x*w1[0]+tv.y*w1[1]+tv.z*w1[2]+tv.w*w1[3];
    }
  }
  float w2a = W2[t], w2b = W2[t+64];
  float bb = b2[0];
  #pragma unroll
  for(int r=0;r<8;r++){
    float o = fmaxf(a0[r],0.f)*w2a + fmaxf(a1[r],0.f)*w2b;
    #pragma unroll
    for(int m=1;m<64;m<<=1) o += __shfl_xor(o,m,64);
    if(t == 0) out[c0 + r] = o + bb;
  }
}

// ---------------------------------------------------------------- launch
extern "C" void kernel_launch(void* const* d_in, const int* in_sizes, int n_in,
                              void* d_out, int out_size, void* d_ws, size_t ws_size,
                              hipStream_t stream){
  const float* L0   = (const float*)d_in[0];
  const float* lng  = (const float*)d_in[1];
  const float* lnb  = (const float*)d_in[2];
  const float* CuW1 = (const float*)d_in[3];
  const float* Cub1 = (const float*)d_in[4];
  const float* CuW2 = (const float*)d_in[5];
  const float* Cub2 = (const float*)d_in[6];
  const float* LuW1 = (const float*)d_in[7];
  const float* Lub1 = (const float*)d_in[8];
  const float* LuW2 = (const float*)d_in[9];
  const float* Lub2 = (const float*)d_in[10];
  const float* VdW1 = (const float*)d_in[11];
  const float* Vdb1 = (const float*)d_in[12];
  const float* VdW2 = (const float*)d_in[13];
  const float* Vdb2 = (const float*)d_in[14];
  const float* VcW1 = (const float*)d_in[15];
  const float* Vcb1 = (const float*)d_in[16];
  const float* VcW2 = (const float*)d_in[17];
  const float* Vcb2 = (const float*)d_in[18];
  const float* CsW1 = (const float*)d_in[19];
  const float* Csb1 = (const float*)d_in[20];
  const float* CsW2 = (const float*)d_in[21];
  const float* Csb2 = (const float*)d_in[22];
  const int* cidx = (const int*)d_in[23];
  const int* lidx = (const int*)d_in[24];
  const int  ne   = in_sizes[23];

  float* ws   = (float*)d_ws;
  float* Lh   = ws;                        // 25,600,000 f32
  float* C    = ws + 25600000;             // 38,400,000 f32 -> end 64,000,000
  float* st   = ws + 64000000;             // 512: sum|sumsq|mean|isd
  int*   ib   = (int*)(ws + 64000512);     // int region
  int*   Pc   = ib;                        // PAD_C = 300,032
  int*   Pl   = ib + PAD_C;                // PAD_L = 200,704
  int*   clit = ib + PAD_C + PAD_L;        // 1,000,000
  int*   lcl  = clit + 1000000;            // 1,000,000
  int*   psum = lcl + 1000000;             // 512
  // total ws ~= 266 MB
  float* out = (float*)d_out;              // fp32: drat|core|c_core

  k_init_lh<<<100000, 256, 0, stream>>>(L0, Lh);

  // CSR build (counting sort both directions)
  k_zero4<<<489, 256, 0, stream>>>((float4*)Pc, (PAD_C + PAD_L)/4);
  k_hist<<<(ne+255)/256, 256, 0, stream>>>(cidx, lidx, Pc, Pl, ne);
  k_scan_pass1<<<NB_C, 256, 0, stream>>>(Pc, psum);
  k_scan_pass2<<<1, 512, 0, stream>>>(psum, NB_C);
  k_scan_pass3<<<NB_C, 256, 0, stream>>>(Pc, psum);
  k_scan_pass1<<<NB_L, 256, 0, stream>>>(Pl, psum);
  k_scan_pass2<<<1, 512, 0, stream>>>(psum, NB_L);
  k_scan_pass3<<<NB_L, 256, 0, stream>>>(Pl, psum);
  k_fill<<<(ne+255)/256, 256, 0, stream>>>(cidx, lidx, Pc, Pl, clit, lcl, ne);

  for(int hop=0; hop<4; hop++){
    k_zero4<<<1, 256, 0, stream>>>((float4*)st, 128);
    k_clause_fused<<<18750, 256, 0, stream>>>(Pc, clit, Lh, CuW1, Cub1, CuW2, Cub2, C);
    k_colstats<<<512, 256, 0, stream>>>(C, st);
    k_finstats<<<1, 128, 0, stream>>>(st);
    k_lit_fused<<<6250, 256, 0, stream>>>(Pl, lcl, C, st, LuW1, Lub1, LuW2, Lub2, lng, lnb, Lh);
  }
  k_head_v<<<6250, 256, 0, stream>>>(Lh, VdW1, Vdb1, VdW2, Vdb2, VcW1, Vcb1, VcW2, Vcb2, out);
  k_head_c<<<37500, 64, 0, stream>>>(C, st, CsW1, Csb1, CsW2, Csb2, out + 200000);
}

// Round 11
// 7406.374 us; speedup vs baseline: 1.3081x; 1.2378x over previous
//
#include <hip/hip_runtime.h>
#include <hip/hip_bf16.h>

#define NCL   300000
#define NLIT  200000
#define HALFL 100000
#define NVAR  100000

#define NB_C  293            // 293*1024 = 300032 >= NCL
#define PAD_C (NB_C*1024)
#define NB_L  196            // 196*1024 = 200704 >= NLIT
#define PAD_L (NB_L*1024)

__device__ __forceinline__ int imax(int a, int b){ return a > b ? a : b; }

// ---------------------------------------------------------------- utilities
__global__ void k_init_lh(const float* __restrict__ L0, float* __restrict__ Lh){
  int i = blockIdx.x*256 + threadIdx.x;            // 25,600,000 total
  Lh[i] = L0[i & 127];
}

__global__ void k_zero4(float4* __restrict__ p, int n4){
  int i = blockIdx.x*256 + threadIdx.x;
  if(i < n4) p[i] = make_float4(0.f,0.f,0.f,0.f);
}

// ---------------------------------------------------------------- CSR build
__global__ __launch_bounds__(256) void k_hist(const int* __restrict__ ci, const int* __restrict__ li,
    int* __restrict__ Pc, int* __restrict__ Pl, int ne){
  int e = blockIdx.x*256 + threadIdx.x;
  if(e < ne){ atomicAdd(&Pc[ci[e]], 1); atomicAdd(&Pl[li[e]], 1); }
}

__global__ __launch_bounds__(256) void k_scan_pass1(const int* __restrict__ P, int* __restrict__ psum){
  __shared__ int red[256];
  int t = threadIdx.x;
  int4 v = *(const int4*)&P[blockIdx.x*1024 + t*4];
  red[t] = v.x + v.y + v.z + v.w;
  __syncthreads();
  for(int ofs=128; ofs>0; ofs>>=1){
    if(t < ofs) red[t] += red[t+ofs];
    __syncthreads();
  }
  if(t == 0) psum[blockIdx.x] = red[0];
}

__global__ __launch_bounds__(512) void k_scan_pass2(int* __restrict__ psum, int nb){
  __shared__ int sA[512], sB[512];
  int t = threadIdx.x;
  sA[t] = (t < nb) ? psum[t] : 0;
  __syncthreads();
  int* src = sA; int* dst = sB;
  for(int ofs=1; ofs<512; ofs<<=1){
    int x = src[t];
    if(t >= ofs) x += src[t-ofs];
    dst[t] = x;
    __syncthreads();
    int* tmp = src; src = dst; dst = tmp;
  }
  psum[t] = t ? src[t-1] : 0;    // exclusive
}

__global__ __launch_bounds__(256) void k_scan_pass3(int* __restrict__ P, const int* __restrict__ psum){
  __shared__ int sA[256], sB[256];
  int t = threadIdx.x;
  int base = blockIdx.x*1024 + t*4;
  int4 v = *(const int4*)&P[base];
  int tsum = v.x + v.y + v.z + v.w;
  sA[t] = tsum;
  __syncthreads();
  int* src = sA; int* dst = sB;
  for(int ofs=1; ofs<256; ofs<<=1){
    int x = src[t];
    if(t >= ofs) x += src[t-ofs];
    dst[t] = x;
    __syncthreads();
    int* tmp = src; src = dst; dst = tmp;
  }
  int excl = psum[blockIdx.x] + src[t] - tsum;   // exclusive across whole array
  int4 o;
  o.x = excl;
  o.y = o.x + v.x;
  o.z = o.y + v.y;
  o.w = o.z + v.z;
  *(int4*)&P[base] = o;
}

// After k_fill, P[c] holds END offset of row c; begin(c) = c ? P[c-1] : 0.
__global__ __launch_bounds__(256) void k_fill(const int* __restrict__ ci, const int* __restrict__ li,
    int* __restrict__ Pc, int* __restrict__ Pl, int* __restrict__ clit, int* __restrict__ lcl, int ne){
  int e = blockIdx.x*256 + threadIdx.x;
  if(e < ne){
    int c = ci[e], l = li[e];
    clit[atomicAdd(&Pc[c], 1)] = l;
    lcl [atomicAdd(&Pl[l], 1)] = c;
  }
}

// ------------------- clause side: CSR gather + MLP 256->256->128 -> C (raw)
// 64 thr (1 wave), 8 clauses/block, 8.4 KB LDS (xs reused for hidden).
// Gather: 2 groups of 4 rows INTERLEAVED -> 4 independent load chains
// in flight per wave (vs 1 serial chain). Rows are wave-uniform; predication
// via mask-FMA. Edge order per row preserved (bitwise-identical results).
__global__ __launch_bounds__(64) void k_clause_fused(
    const int* __restrict__ Pc, const int* __restrict__ clit,
    const float* __restrict__ Lh,
    const float* __restrict__ W1, const float* __restrict__ b1,
    const float* __restrict__ W2, const float* __restrict__ b2, float* __restrict__ Y){
  __shared__ float xs[8][260];
  __shared__ int rng[9];
  const int t = threadIdx.x;
  const int r0 = blockIdx.x * 8;

  if(t < 9) rng[t] = (r0 + t == 0) ? 0 : Pc[r0 + t - 1];
  __syncthreads();

  { // gather: lanes 0-31 direct half, 32-63 flipped half; float4/lane
    const int half = t >> 5, f4 = (t & 31) * 4;
    #pragma unroll
    for(int g=0; g<2; g++){
      const int rb4 = g*4;
      const int b0=rng[rb4+0], n0=rng[rb4+1];
      const int b1=rng[rb4+1], n1=rng[rb4+2];
      const int b2=rng[rb4+2], n2=rng[rb4+3];
      const int b3=rng[rb4+3], n3=rng[rb4+4];
      float4 a0=make_float4(0.f,0.f,0.f,0.f), a1=a0, a2=a0, a3=a0;
      int l0=(b0<n0)?clit[b0]:0, l1=(b1<n1)?clit[b1]:0;
      int l2=(b2<n2)?clit[b2]:0, l3=(b3<n3)?clit[b3]:0;
      const int md = imax(imax(n0-b0,n1-b1), imax(n2-b2,n3-b3));
      for(int s=0; s<md; s++){
        int s0 = half ? ((l0<HALFL)?l0+HALFL:l0-HALFL) : l0;
        int s1 = half ? ((l1<HALFL)?l1+HALFL:l1-HALFL) : l1;
        int s2 = half ? ((l2<HALFL)?l2+HALFL:l2-HALFL) : l2;
        int s3 = half ? ((l3<HALFL)?l3+HALFL:l3-HALFL) : l3;
        float4 v0 = *(const float4*)&Lh[(size_t)s0*128 + f4];
        float4 v1 = *(const float4*)&Lh[(size_t)s1*128 + f4];
        float4 v2 = *(const float4*)&Lh[(size_t)s2*128 + f4];
        float4 v3 = *(const float4*)&Lh[(size_t)s3*128 + f4];
        int p0=(b0+s+1<n0)?clit[b0+s+1]:0;      // prefetch next indices
        int p1=(b1+s+1<n1)?clit[b1+s+1]:0;
        int p2=(b2+s+1<n2)?clit[b2+s+1]:0;
        int p3=(b3+s+1<n3)?clit[b3+s+1]:0;
        float m0=(b0+s<n0)?1.f:0.f, m1=(b1+s<n1)?1.f:0.f;
        float m2=(b2+s<n2)?1.f:0.f, m3=(b3+s<n3)?1.f:0.f;
        a0.x=fmaf(m0,v0.x,a0.x); a0.y=fmaf(m0,v0.y,a0.y); a0.z=fmaf(m0,v0.z,a0.z); a0.w=fmaf(m0,v0.w,a0.w);
        a1.x=fmaf(m1,v1.x,a1.x); a1.y=fmaf(m1,v1.y,a1.y); a1.z=fmaf(m1,v1.z,a1.z); a1.w=fmaf(m1,v1.w,a1.w);
        a2.x=fmaf(m2,v2.x,a2.x); a2.y=fmaf(m2,v2.y,a2.y); a2.z=fmaf(m2,v2.z,a2.z); a2.w=fmaf(m2,v2.w,a2.w);
        a3.x=fmaf(m3,v3.x,a3.x); a3.y=fmaf(m3,v3.y,a3.y); a3.z=fmaf(m3,v3.z,a3.z); a3.w=fmaf(m3,v3.w,a3.w);
        l0=p0; l1=p1; l2=p2; l3=p3;
      }
      *(float4*)&xs[rb4+0][(half<<7)+f4] = a0;
      *(float4*)&xs[rb4+1][(half<<7)+f4] = a1;
      *(float4*)&xs[rb4+2][(half<<7)+f4] = a2;
      *(float4*)&xs[rb4+3][(half<<7)+f4] = a3;
    }
  }
  __syncthreads();

  float h[4][8];
  { // layer 1: 256->256, 4 rows x 8 cols per thread
    const int c0 = (t & 31)*8, rb = (t >> 5)*4;
    #pragma unroll
    for(int cc=0;cc<8;cc++){
      float bv = b1[c0+cc];
      #pragma unroll
      for(int r=0;r<4;r++) h[r][cc]=bv;
    }
    for(int k=0;k<256;k+=4){
      float4 xv[4];
      #pragma unroll
      for(int r=0;r<4;r++) xv[r] = *(const float4*)&xs[rb+r][k];
      #pragma unroll
      for(int kk=0;kk<4;kk++){
        float4 wa = *(const float4*)&W1[(size_t)(k+kk)*256 + c0];
        float4 wb = *(const float4*)&W1[(size_t)(k+kk)*256 + c0 + 4];
        #pragma unroll
        for(int r=0;r<4;r++){
          float x = (kk==0)?xv[r].x:(kk==1)?xv[r].y:(kk==2)?xv[r].z:xv[r].w;
          h[r][0]=fmaf(x,wa.x,h[r][0]); h[r][1]=fmaf(x,wa.y,h[r][1]);
          h[r][2]=fmaf(x,wa.z,h[r][2]); h[r][3]=fmaf(x,wa.w,h[r][3]);
          h[r][4]=fmaf(x,wb.x,h[r][4]); h[r][5]=fmaf(x,wb.y,h[r][5]);
          h[r][6]=fmaf(x,wb.z,h[r][6]); h[r][7]=fmaf(x,wb.w,h[r][7]);
        }
      }
    }
  }
  __syncthreads();               // xs reads complete -> safe to overwrite
  { const int c0 = (t & 31)*8, rb = (t >> 5)*4;
    #pragma unroll
    for(int r=0;r<4;r++){
      *(float4*)&xs[rb+r][c0]   = make_float4(fmaxf(h[r][0],0.f),fmaxf(h[r][1],0.f),fmaxf(h[r][2],0.f),fmaxf(h[r][3],0.f));
      *(float4*)&xs[rb+r][c0+4] = make_float4(fmaxf(h[r][4],0.f),fmaxf(h[r][5],0.f),fmaxf(h[r][6],0.f),fmaxf(h[r][7],0.f));
    }
  }
  __syncthreads();

  { // layer 2: 256 -> 128, 2 rows x 8 cols per thread
    const int c0 = (t & 15)*8, rb = (t >> 4)*2;
    float o[2][8];
    #pragma unroll
    for(int cc=0;cc<8;cc++){ float bv = b2[c0+cc]; o[0][cc]=bv; o[1][cc]=bv; }
    for(int k=0;k<256;k+=4){
      float4 xv[2];
      #pragma unroll
      for(int r=0;r<2;r++) xv[r] = *(const float4*)&xs[rb+r][k];
      #pragma unroll
      for(int kk=0;kk<4;kk++){
        float4 wa = *(const float4*)&W2[(size_t)(k+kk)*128 + c0];
        float4 wb = *(const float4*)&W2[(size_t)(k+kk)*128 + c0 + 4];
        #pragma unroll
        for(int r=0;r<2;r++){
          float x = (kk==0)?xv[r].x:(kk==1)?xv[r].y:(kk==2)?xv[r].z:xv[r].w;
          o[r][0]=fmaf(x,wa.x,o[r][0]); o[r][1]=fmaf(x,wa.y,o[r][1]);
          o[r][2]=fmaf(x,wa.z,o[r][2]); o[r][3]=fmaf(x,wa.w,o[r][3]);
          o[r][4]=fmaf(x,wb.x,o[r][4]); o[r][5]=fmaf(x,wb.y,o[r][5]);
          o[r][6]=fmaf(x,wb.z,o[r][6]); o[r][7]=fmaf(x,wb.w,o[r][7]);
        }
      }
    }
    #pragma unroll
    for(int r=0;r<2;r++){
      *(float4*)&Y[(size_t)(r0+rb+r)*128 + c0]     = make_float4(o[r][0],o[r][1],o[r][2],o[r][3]);
      *(float4*)&Y[(size_t)(r0+rb+r)*128 + c0 + 4] = make_float4(o[r][4],o[r][5],o[r][6],o[r][7]);
    }
  }
}

// ---------------------------------------------------------------- col stats
__global__ __launch_bounds__(256) void k_colstats(const float* __restrict__ C, float* __restrict__ st){
  const int t = threadIdx.x, col = t & 127, h = t >> 7;
  float s = 0.f, s2 = 0.f;
  for(int r = blockIdx.x*2 + h; r < NCL; r += 1024){   // grid = 512 blocks
    float v = C[(size_t)r*128 + col];
    s += v; s2 += v*v;
  }
  __shared__ float red[256];
  red[t] = s; __syncthreads();
  if(t < 128) atomicAdd(&st[col], red[t] + red[t+128]);
  __syncthreads();
  red[t] = s2; __syncthreads();
  if(t < 128) atomicAdd(&st[128+col], red[t] + red[t+128]);
}

__global__ void k_finstats(float* st){
  int j = threadIdx.x;
  if(j < 128){
    const float n = (float)NCL;
    float mean = st[j]/n;
    float var = (st[128+j] - n*mean*mean) / (n - 1.f);   // ddof=1
    var = fmaxf(var, 0.f);
    st[256+j] = mean;
    st[384+j] = 1.f/(sqrtf(var) + 1e-10f);
  }
}

// -------- literal side: gather (analytically normalized) + MLP + res + LN
// 64 thr, 8 literals/block, 4.3 KB LDS. Gather: each half-wave owns 4 rows,
// INTERLEAVED -> 4 chains in flight.
__global__ __launch_bounds__(64) void k_lit_fused(
    const int* __restrict__ Pl, const int* __restrict__ lcl,
    const float* __restrict__ C, const float* __restrict__ st,
    const float* __restrict__ W1, const float* __restrict__ b1,
    const float* __restrict__ W2, const float* __restrict__ b2,
    const float* __restrict__ lng, const float* __restrict__ lnb, float* __restrict__ Lh){
  __shared__ float xs[8][132];
  __shared__ int rng[9];
  const int t = threadIdx.x;
  const int r0 = blockIdx.x * 8;

  if(t < 9) rng[t] = (r0 + t == 0) ? 0 : Pl[r0 + t - 1];
  __syncthreads();

  { const int half = t >> 5, f4 = (t & 31) * 4;
    float4 mean4 = *(const float4*)&st[256+f4];
    float4 isd4  = *(const float4*)&st[384+f4];
    const int rb4 = half*4;
    const int b0=rng[rb4+0], n0=rng[rb4+1];
    const int b1=rng[rb4+1], n1=rng[rb4+2];
    const int b2=rng[rb4+2], n2=rng[rb4+3];
    const int b3=rng[rb4+3], n3=rng[rb4+4];
    float4 a0=make_float4(0.f,0.f,0.f,0.f), a1=a0, a2=a0, a3=a0;
    int l0=(b0<n0)?lcl[b0]:0, l1=(b1<n1)?lcl[b1]:0;
    int l2=(b2<n2)?lcl[b2]:0, l3=(b3<n3)?lcl[b3]:0;
    const int md = imax(imax(n0-b0,n1-b1), imax(n2-b2,n3-b3));
    for(int s=0; s<md; s++){
      float4 v0 = *(const float4*)&C[(size_t)l0*128 + f4];
      float4 v1 = *(const float4*)&C[(size_t)l1*128 + f4];
      float4 v2 = *(const float4*)&C[(size_t)l2*128 + f4];
      float4 v3 = *(const float4*)&C[(size_t)l3*128 + f4];
      int p0=(b0+s+1<n0)?lcl[b0+s+1]:0;
      int p1=(b1+s+1<n1)?lcl[b1+s+1]:0;
      int p2=(b2+s+1<n2)?lcl[b2+s+1]:0;
      int p3=(b3+s+1<n3)?lcl[b3+s+1]:0;
      float m0=(b0+s<n0)?1.f:0.f, m1=(b1+s<n1)?1.f:0.f;
      float m2=(b2+s<n2)?1.f:0.f, m3=(b3+s<n3)?1.f:0.f;
      a0.x=fmaf(m0,v0.x,a0.x); a0.y=fmaf(m0,v0.y,a0.y); a0.z=fmaf(m0,v0.z,a0.z); a0.w=fmaf(m0,v0.w,a0.w);
      a1.x=fmaf(m1,v1.x,a1.x); a1.y=fmaf(m1,v1.y,a1.y); a1.z=fmaf(m1,v1.z,a1.z); a1.w=fmaf(m1,v1.w,a1.w);
      a2.x=fmaf(m2,v2.x,a2.x); a2.y=fmaf(m2,v2.y,a2.y); a2.z=fmaf(m2,v2.z,a2.z); a2.w=fmaf(m2,v2.w,a2.w);
      a3.x=fmaf(m3,v3.x,a3.x); a3.y=fmaf(m3,v3.y,a3.y); a3.z=fmaf(m3,v3.z,a3.z); a3.w=fmaf(m3,v3.w,a3.w);
      l0=p0; l1=p1; l2=p2; l3=p3;
    }
    float d0=(float)(n0-b0), d1=(float)(n1-b1), d2=(float)(n2-b2), d3=(float)(n3-b3);
    a0.x=(a0.x-d0*mean4.x)*isd4.x; a0.y=(a0.y-d0*mean4.y)*isd4.y; a0.z=(a0.z-d0*mean4.z)*isd4.z; a0.w=(a0.w-d0*mean4.w)*isd4.w;
    a1.x=(a1.x-d1*mean4.x)*isd4.x; a1.y=(a1.y-d1*mean4.y)*isd4.y; a1.z=(a1.z-d1*mean4.z)*isd4.z; a1.w=(a1.w-d1*mean4.w)*isd4.w;
    a2.x=(a2.x-d2*mean4.x)*isd4.x; a2.y=(a2.y-d2*mean4.y)*isd4.y; a2.z=(a2.z-d2*mean4.z)*isd4.z; a2.w=(a2.w-d2*mean4.w)*isd4.w;
    a3.x=(a3.x-d3*mean4.x)*isd4.x; a3.y=(a3.y-d3*mean4.y)*isd4.y; a3.z=(a3.z-d3*mean4.z)*isd4.z; a3.w=(a3.w-d3*mean4.w)*isd4.w;
    *(float4*)&xs[rb4+0][f4]=a0;
    *(float4*)&xs[rb4+1][f4]=a1;
    *(float4*)&xs[rb4+2][f4]=a2;
    *(float4*)&xs[rb4+3][f4]=a3;
  }
  __syncthreads();

  const int c0 = (t & 15)*8, rb = (t >> 4)*2;
  float h[2][8];
  #pragma unroll
  for(int cc=0;cc<8;cc++){ float bv = b1[c0+cc]; h[0][cc]=bv; h[1][cc]=bv; }
  for(int k=0;k<128;k+=4){
    float4 xv[2];
    #pragma unroll
    for(int r=0;r<2;r++) xv[r] = *(const float4*)&xs[rb+r][k];
    #pragma unroll
    for(int kk=0;kk<4;kk++){
      float4 wa = *(const float4*)&W1[(size_t)(k+kk)*128 + c0];
      float4 wb = *(const float4*)&W1[(size_t)(k+kk)*128 + c0 + 4];
      #pragma unroll
      for(int r=0;r<2;r++){
        float x = (kk==0)?xv[r].x:(kk==1)?xv[r].y:(kk==2)?xv[r].z:xv[r].w;
        h[r][0]=fmaf(x,wa.x,h[r][0]); h[r][1]=fmaf(x,wa.y,h[r][1]);
        h[r][2]=fmaf(x,wa.z,h[r][2]); h[r][3]=fmaf(x,wa.w,h[r][3]);
        h[r][4]=fmaf(x,wb.x,h[r][4]); h[r][5]=fmaf(x,wb.y,h[r][5]);
        h[r][6]=fmaf(x,wb.z,h[r][6]); h[r][7]=fmaf(x,wb.w,h[r][7]);
      }
    }
  }
  __syncthreads();
  #pragma unroll
  for(int r=0;r<2;r++){
    *(float4*)&xs[rb+r][c0]   = make_float4(fmaxf(h[r][0],0.f),fmaxf(h[r][1],0.f),fmaxf(h[r][2],0.f),fmaxf(h[r][3],0.f));
    *(float4*)&xs[rb+r][c0+4] = make_float4(fmaxf(h[r][4],0.f),fmaxf(h[r][5],0.f),fmaxf(h[r][6],0.f),fmaxf(h[r][7],0.f));
  }
  __syncthreads();

  float y[2][8];
  #pragma unroll
  for(int cc=0;cc<8;cc++){ float bv = b2[c0+cc]; y[0][cc]=bv; y[1][cc]=bv; }
  for(int k=0;k<128;k+=4){
    float4 xv[2];
    #pragma unroll
    for(int r=0;r<2;r++) xv[r] = *(const float4*)&xs[rb+r][k];
    #pragma unroll
    for(int kk=0;kk<4;kk++){
      float4 wa = *(const float4*)&W2[(size_t)(k+kk)*128 + c0];
      float4 wb = *(const float4*)&W2[(size_t)(k+kk)*128 + c0 + 4];
      #pragma unroll
      for(int r=0;r<2;r++){
        float x = (kk==0)?xv[r].x:(kk==1)?xv[r].y:(kk==2)?xv[r].z:xv[r].w;
        y[r][0]=fmaf(x,wa.x,y[r][0]); y[r][1]=fmaf(x,wa.y,y[r][1]);
        y[r][2]=fmaf(x,wa.z,y[r][2]); y[r][3]=fmaf(x,wa.w,y[r][3]);
        y[r][4]=fmaf(x,wb.x,y[r][4]); y[r][5]=fmaf(x,wb.y,y[r][5]);
        y[r][6]=fmaf(x,wb.z,y[r][6]); y[r][7]=fmaf(x,wb.w,y[r][7]);
      }
    }
  }

  float gv[8], bv[8];
  #pragma unroll
  for(int cc=0;cc<8;cc++){ gv[cc]=lng[c0+cc]; bv[cc]=lnb[c0+cc]; }
  #pragma unroll
  for(int r=0;r<2;r++){
    size_t row = (size_t)(r0 + rb + r);
    float4 la = *(const float4*)&Lh[row*128 + c0];
    float4 lc = *(const float4*)&Lh[row*128 + c0 + 4];
    y[r][0] += 0.1f*la.x; y[r][1] += 0.1f*la.y; y[r][2] += 0.1f*la.z; y[r][3] += 0.1f*la.w;
    y[r][4] += 0.1f*lc.x; y[r][5] += 0.1f*lc.y; y[r][6] += 0.1f*lc.z; y[r][7] += 0.1f*lc.w;
    float s = 0.f, s2 = 0.f;
    #pragma unroll
    for(int cc=0;cc<8;cc++){ s += y[r][cc]; s2 += y[r][cc]*y[r][cc]; }
    #pragma unroll
    for(int m=1;m<16;m<<=1){ s += __shfl_xor(s,m,64); s2 += __shfl_xor(s2,m,64); }
    float mean = s*(1.f/128.f);
    float var  = s2*(1.f/128.f) - mean*mean;
    float rs   = rsqrtf(fmaxf(var, 0.f) + 1e-5f);
    float o[8];
    #pragma unroll
    for(int cc=0;cc<8;cc++) o[cc] = (y[r][cc]-mean)*rs*gv[cc] + bv[cc];
    *(float4*)&Lh[row*128 + c0]     = make_float4(o[0],o[1],o[2],o[3]);
    *(float4*)&Lh[row*128 + c0 + 4] = make_float4(o[4],o[5],o[6],o[7]);
  }
}

// ---------------------------------------------------------------- heads
__global__ __launch_bounds__(64) void k_head_v(const float* __restrict__ Lh,
    const float* __restrict__ W1d, const float* __restrict__ b1d, const float* __restrict__ W2d, const float* __restrict__ b2d,
    const float* __restrict__ W1c, const float* __restrict__ b1c, const float* __restrict__ W2c, const float* __restrict__ b2c,
    float* __restrict__ out){
  __shared__ float xs[8][256];
  const int t = threadIdx.x;
  const size_t v0 = (size_t)blockIdx.x * 8;
  #pragma unroll
  for(int r=0;r<8;r++){
    xs[r][t]     = Lh[(v0+r)*128 + t];
    xs[r][t+64]  = Lh[(v0+r)*128 + t + 64];
    xs[r][t+128] = Lh[(v0+r+HALFL)*128 + t];
    xs[r][t+192] = Lh[(v0+r+HALFL)*128 + t + 64];
  }
  __syncthreads();
  for(int hd=0; hd<2; hd++){
    const float* W1 = hd ? W1c : W1d;
    const float* b1 = hd ? b1c : b1d;
    const float* W2 = hd ? W2c : W2d;
    const float* b2 = hd ? b2c : b2d;
    float acc[8][4];
    #pragma unroll
    for(int c=0;c<4;c++){
      float bvv = b1[t + 64*c];
      #pragma unroll
      for(int r=0;r<8;r++) acc[r][c]=bvv;
    }
    for(int k=0;k<256;k+=4){
      float w[4][4];
      #pragma unroll
      for(int kk=0;kk<4;kk++)
        #pragma unroll
        for(int c=0;c<4;c++) w[kk][c] = W1[(size_t)(k+kk)*256 + t + 64*c];
      #pragma unroll
      for(int r=0;r<8;r++){
        float4 tv = *(const float4*)&xs[r][k];
        #pragma unroll
        for(int c=0;c<4;c++)
          acc[r][c] += tv.x*w[0][c] + tv.y*w[1][c] + tv.z*w[2][c] + tv.w*w[3][c];
      }
    }
    float w2[4];
    #pragma unroll
    for(int c=0;c<4;c++) w2[c] = W2[t + 64*c];
    float bb = b2[0];
    #pragma unroll
    for(int r=0;r<8;r++){
      float o = fmaxf(acc[r][0],0.f)*w2[0] + fmaxf(acc[r][1],0.f)*w2[1]
              + fmaxf(acc[r][2],0.f)*w2[2] + fmaxf(acc[r][3],0.f)*w2[3];
      #pragma unroll
      for(int m=1;m<64;m<<=1) o += __shfl_xor(o,m,64);
      if(t == 0) out[(size_t)hd*NVAR + v0 + r] = o + bb;
    }
  }
}

// 64 thr, 8 clauses/block; normalizes C on load.
__global__ __launch_bounds__(64) void k_head_c(const float* __restrict__ C,
    const float* __restrict__ st,
    const float* __restrict__ W1, const float* __restrict__ b1,
    const float* __restrict__ W2, const float* __restrict__ b2,
    float* __restrict__ out){
  __shared__ float xs[8][128];
  const int t = threadIdx.x;
  const size_t c0 = (size_t)blockIdx.x * 8;
  { float m0 = st[256+t], m1 = st[256+t+64];
    float i0 = st[384+t], i1 = st[384+t+64];
    #pragma unroll
    for(int r=0;r<8;r++){
      xs[r][t]    = (C[(c0+r)*128 + t]      - m0) * i0;
      xs[r][t+64] = (C[(c0+r)*128 + t + 64] - m1) * i1;
    }
  }
  __syncthreads();
  float a0[8], a1[8];
  float bv0 = b1[t], bv1 = b1[t+64];
  #pragma unroll
  for(int r=0;r<8;r++){ a0[r]=bv0; a1[r]=bv1; }
  for(int k=0;k<128;k+=4){
    float w0[4], w1[4];
    #pragma unroll
    for(int kk=0;kk<4;kk++){ w0[kk]=W1[(size_t)(k+kk)*128 + t]; w1[kk]=W1[(size_t)(k+kk)*128 + t + 64]; }
    #pragma unroll
    for(int r=0;r<8;r++){
      float4 tv = *(const float4*)&xs[r][k];
      a0[r] += tv.x*w0[0]+tv.y*w0[1]+tv.z*w0[2]+tv.w*w0[3];
      a1[r] += tv.x*w1[0]+tv.y*w1[1]+tv.z*w1[2]+tv.w*w1[3];
    }
  }
  float w2a = W2[t], w2b = W2[t+64];
  float bb = b2[0];
  #pragma unroll
  for(int r=0;r<8;r++){
    float o = fmaxf(a0[r],0.f)*w2a + fmaxf(a1[r],0.f)*w2b;
    #pragma unroll
    for(int m=1;m<64;m<<=1) o += __shfl_xor(o,m,64);
    if(t == 0) out[c0 + r] = o + bb;
  }
}

// ---------------------------------------------------------------- launch
extern "C" void kernel_launch(void* const* d_in, const int* in_sizes, int n_in,
                              void* d_out, int out_size, void* d_ws, size_t ws_size,
                              hipStream_t stream){
  const float* L0   = (const float*)d_in[0];
  const float* lng  = (const float*)d_in[1];
  const float* lnb  = (const float*)d_in[2];
  const float* CuW1 = (const float*)d_in[3];
  const float* Cub1 = (const float*)d_in[4];
  const float* CuW2 = (const float*)d_in[5];
  const float* Cub2 = (const float*)d_in[6];
  const float* LuW1 = (const float*)d_in[7];
  const float* Lub1 = (const float*)d_in[8];
  const float* LuW2 = (const float*)d_in[9];
  const float* Lub2 = (const float*)d_in[10];
  const float* VdW1 = (const float*)d_in[11];
  const float* Vdb1 = (const float*)d_in[12];
  const float* VdW2 = (const float*)d_in[13];
  const float* Vdb2 = (const float*)d_in[14];
  const float* VcW1 = (const float*)d_in[15];
  const float* Vcb1 = (const float*)d_in[16];
  const float* VcW2 = (const float*)d_in[17];
  const float* Vcb2 = (const float*)d_in[18];
  const float* CsW1 = (const float*)d_in[19];
  const float* Csb1 = (const float*)d_in[20];
  const float* CsW2 = (const float*)d_in[21];
  const float* Csb2 = (const float*)d_in[22];
  const int* cidx = (const int*)d_in[23];
  const int* lidx = (const int*)d_in[24];
  const int  ne   = in_sizes[23];

  float* ws   = (float*)d_ws;
  float* Lh   = ws;                        // 25,600,000 f32
  float* C    = ws + 25600000;             // 38,400,000 f32 -> end 64,000,000
  float* st   = ws + 64000000;             // 512: sum|sumsq|mean|isd
  int*   ib   = (int*)(ws + 64000512);     // int region
  int*   Pc   = ib;                        // PAD_C = 300,032
  int*   Pl   = ib + PAD_C;                // PAD_L = 200,704
  int*   clit = ib + PAD_C + PAD_L;        // 1,000,000
  int*   lcl  = clit + 1000000;            // 1,000,000
  int*   psum = lcl + 1000000;             // 512
  // total ws ~= 266 MB
  float* out = (float*)d_out;              // fp32: drat|core|c_core

  k_init_lh<<<100000, 256, 0, stream>>>(L0, Lh);

  // CSR build (counting sort both directions)
  k_zero4<<<489, 256, 0, stream>>>((float4*)Pc, (PAD_C + PAD_L)/4);
  k_hist<<<(ne+255)/256, 256, 0, stream>>>(cidx, lidx, Pc, Pl, ne);
  k_scan_pass1<<<NB_C, 256, 0, stream>>>(Pc, psum);
  k_scan_pass2<<<1, 512, 0, stream>>>(psum, NB_C);
  k_scan_pass3<<<NB_C, 256, 0, stream>>>(Pc, psum);
  k_scan_pass1<<<NB_L, 256, 0, stream>>>(Pl, psum);
  k_scan_pass2<<<1, 512, 0, stream>>>(psum, NB_L);
  k_scan_pass3<<<NB_L, 256, 0, stream>>>(Pl, psum);
  k_fill<<<(ne+255)/256, 256, 0, stream>>>(cidx, lidx, Pc, Pl, clit, lcl, ne);

  for(int hop=0; hop<4; hop++){
    k_zero4<<<1, 256, 0, stream>>>((float4*)st, 128);
    k_clause_fused<<<37500, 64, 0, stream>>>(Pc, clit, Lh, CuW1, Cub1, CuW2, Cub2, C);
    k_colstats<<<512, 256, 0, stream>>>(C, st);
    k_finstats<<<1, 128, 0, stream>>>(st);
    k_lit_fused<<<25000, 64, 0, stream>>>(Pl, lcl, C, st, LuW1, Lub1, LuW2, Lub2, lng, lnb, Lh);
  }
  k_head_v<<<12500, 64, 0, stream>>>(Lh, VdW1, Vdb1, VdW2, Vdb2, VcW1, Vcb1, VcW2, Vcb2, out);
  k_head_c<<<37500, 64, 0, stream>>>(C, st, CsW1, Csb1, CsW2, Csb2, out + 200000);
}

// Round 13
// 4590.913 us; speedup vs baseline: 2.1103x; 1.6133x over previous
//
#include <hip/hip_runtime.h>
#include <hip/hip_bf16.h>

#define NCL   300000
#define NLIT  200000
#define HALFL 100000
#define NVAR  100000

#define NB_C  293            // 293*1024 = 300032 >= NCL
#define PAD_C (NB_C*1024)
#define NB_L  196            // 196*1024 = 200704 >= NLIT
#define PAD_L (NB_L*1024)

typedef __attribute__((ext_vector_type(8))) short short8;   // 8 bf16 (4 VGPRs)
typedef __attribute__((ext_vector_type(4))) float f32x4;    // MFMA acc

__device__ __forceinline__ unsigned short f2b(float x){     // fp32 -> bf16 RNE
  union{float f; unsigned int u;} v; v.f = x;
  unsigned int r = v.u + 0x7FFF + ((v.u >> 16) & 1);
  return (unsigned short)(r >> 16);
}
__device__ __forceinline__ float b2f(unsigned short u){
  union{unsigned int i; float f;} x; x.i = ((unsigned int)u) << 16; return x.f;
}

// ---------------------------------------------------------------- utilities
__global__ void k_init_lh(const float* __restrict__ L0, float* __restrict__ Lh){
  int i = blockIdx.x*256 + threadIdx.x;            // 25,600,000 total
  Lh[i] = L0[i & 127];
}

__global__ void k_zero4(float4* __restrict__ p, int n4){
  int i = blockIdx.x*256 + threadIdx.x;
  if(i < n4) p[i] = make_float4(0.f,0.f,0.f,0.f);
}

// Pack fp32 row-major W[K][N] into hi/lo bf16 MFMA B-fragment order:
// frag[((nt*(K/32)+kt)*64 + lane)*8 + j] <- W[kt*32+(lane>>4)*8+j][nt*16+(lane&15)]
__global__ void k_pack_w(const float* __restrict__ W, short* __restrict__ Whi,
                         short* __restrict__ Wlo, int K, int N){
  int i = blockIdx.x*256 + threadIdx.x;
  if(i >= K*N) return;
  int j  = i & 7;
  int L  = (i >> 3) & 63;
  int kt = (i >> 9) % (K >> 5);
  int nt = (i >> 9) / (K >> 5);
  int k = kt*32 + ((L >> 4) << 3) + j;
  int n = nt*16 + (L & 15);
  float w = W[(size_t)k*N + n];
  unsigned short hi = f2b(w);
  Whi[i] = (short)hi;
  Wlo[i] = (short)f2b(w - b2f(hi));
}

// ---------------------------------------------------------------- CSR build
__global__ __launch_bounds__(256) void k_hist(const int* __restrict__ ci, const int* __restrict__ li,
    int* __restrict__ Pc, int* __restrict__ Pl, int ne){
  int e = blockIdx.x*256 + threadIdx.x;
  if(e < ne){ atomicAdd(&Pc[ci[e]], 1); atomicAdd(&Pl[li[e]], 1); }
}

__global__ __launch_bounds__(256) void k_scan_pass1(const int* __restrict__ P, int* __restrict__ psum){
  __shared__ int red[256];
  int t = threadIdx.x;
  int4 v = *(const int4*)&P[blockIdx.x*1024 + t*4];
  red[t] = v.x + v.y + v.z + v.w;
  __syncthreads();
  for(int ofs=128; ofs>0; ofs>>=1){
    if(t < ofs) red[t] += red[t+ofs];
    __syncthreads();
  }
  if(t == 0) psum[blockIdx.x] = red[0];
}

__global__ __launch_bounds__(512) void k_scan_pass2(int* __restrict__ psum, int nb){
  __shared__ int sA[512], sB[512];
  int t = threadIdx.x;
  sA[t] = (t < nb) ? psum[t] : 0;
  __syncthreads();
  int* src = sA; int* dst = sB;
  for(int ofs=1; ofs<512; ofs<<=1){
    int x = src[t];
    if(t >= ofs) x += src[t-ofs];
    dst[t] = x;
    __syncthreads();
    int* tmp = src; src = dst; dst = tmp;
  }
  psum[t] = t ? src[t-1] : 0;    // exclusive
}

__global__ __launch_bounds__(256) void k_scan_pass3(int* __restrict__ P, const int* __restrict__ psum){
  __shared__ int sA[256], sB[256];
  int t = threadIdx.x;
  int base = blockIdx.x*1024 + t*4;
  int4 v = *(const int4*)&P[base];
  int tsum = v.x + v.y + v.z + v.w;
  sA[t] = tsum;
  __syncthreads();
  int* src = sA; int* dst = sB;
  for(int ofs=1; ofs<256; ofs<<=1){
    int x = src[t];
    if(t >= ofs) x += src[t-ofs];
    dst[t] = x;
    __syncthreads();
    int* tmp = src; src = dst; dst = tmp;
  }
  int excl = psum[blockIdx.x] + src[t] - tsum;   // exclusive across whole array
  int4 o;
  o.x = excl;
  o.y = o.x + v.x;
  o.z = o.y + v.y;
  o.w = o.z + v.z;
  *(int4*)&P[base] = o;
}

// After k_fill, P[c] holds END offset of row c; begin(c) = c ? P[c-1] : 0.
__global__ __launch_bounds__(256) void k_fill(const int* __restrict__ ci, const int* __restrict__ li,
    int* __restrict__ Pc, int* __restrict__ Pl, int* __restrict__ clit, int* __restrict__ lcl, int ne){
  int e = blockIdx.x*256 + threadIdx.x;
  if(e < ne){
    int c = ci[e], l = li[e];
    clit[atomicAdd(&Pc[c], 1)] = l;
    lcl [atomicAdd(&Pl[l], 1)] = c;
  }
}

// ------ clause side: CSR gather + COMPENSATED bf16 MFMA MLP 256->256->128
// 256 thr (4 waves), 32 clauses/block. LDS: xs[2][32][264] bf16 (hi/lo
// planes, reused for hidden) = 33.8 KB. X*W ~= Xh*Wh + Xh*Wl + Xl*Wh
// (fp32 acc; error ~2^-16 rel, vs 2^-9 for plain bf16 -- survives the
// per-column normalization amplification that killed the 1-pass version).
__global__ __launch_bounds__(256) void k_clause_fused(
    const int* __restrict__ Pc, const int* __restrict__ clit,
    const float* __restrict__ Lh,
    const short* __restrict__ W1h, const short* __restrict__ W1l, const float* __restrict__ b1,
    const short* __restrict__ W2h, const short* __restrict__ W2l, const float* __restrict__ b2,
    float* __restrict__ Y){
  __shared__ short xs[2][32][264];
  __shared__ int rng[33];
  const int t = threadIdx.x;
  const int r0 = blockIdx.x * 32;

  if(t < 33) rng[t] = (r0 + t == 0) ? 0 : Pc[r0 + t - 1];
  __syncthreads();

  const int lane = t & 63, wv = t >> 6;
  { // gather: wave wv rows wv*8..+7; lanes 0-31 direct, 32-63 flipped; f4/lane
    const int half = lane >> 5, f4 = (lane & 31) * 4;
    for(int i=0;i<8;i++){
      int r = wv*8 + i;
      int be = rng[r], en = rng[r+1];
      float4 a = make_float4(0.f,0.f,0.f,0.f);
      int l = (be < en) ? clit[be] : 0;
      for(int e=be; e<en; e++){
        int lnext = (e+1 < en) ? clit[e+1] : 0;          // prefetch next index
        int src = half ? ((l < HALFL) ? l + HALFL : l - HALFL) : l;
        float4 v = *(const float4*)&Lh[(size_t)src*128 + f4];
        a.x += v.x; a.y += v.y; a.z += v.z; a.w += v.w;
        l = lnext;
      }
      unsigned short hx=f2b(a.x), hy=f2b(a.y), hz=f2b(a.z), hw=f2b(a.w);
      unsigned short lx=f2b(a.x-b2f(hx)), ly=f2b(a.y-b2f(hy));
      unsigned short lz=f2b(a.z-b2f(hz)), lw=f2b(a.w-b2f(hw));
      *(uint2*)&xs[0][r][half*128 + f4] =
        make_uint2(((unsigned int)hy<<16)|hx, ((unsigned int)hw<<16)|hz);
      *(uint2*)&xs[1][r][half*128 + f4] =
        make_uint2(((unsigned int)ly<<16)|lx, ((unsigned int)lw<<16)|lz);
    }
  }
  __syncthreads();

  // fragment geometry (A: m=lane&15, k=(lane>>4)*8+j; C/D: col=lane&15,
  // row=(lane>>4)*4+reg -- guide-verified maps)
  const int rt  = wv & 1;                 // row-tile (rows rt*16..+15)
  const int ntb = (wv >> 1) * 8;          // layer-1 n-tile base
  const int am  = rt*16 + (lane & 15);
  const int ak  = (lane >> 4) * 8;

  // layer 1: 256 -> 256  (kt outer, ntl inner; acc persistent)
  f32x4 acc[8];
  #pragma unroll
  for(int ntl=0; ntl<8; ntl++){
    float bv = b1[(ntb+ntl)*16 + (lane & 15)];
    acc[ntl] = (f32x4){bv, bv, bv, bv};
  }
  {
    const short8* Bh = (const short8*)W1h;
    const short8* Bl = (const short8*)W1l;
    #pragma unroll
    for(int kt=0; kt<8; kt++){
      short8 ah = *(const short8*)&xs[0][am][kt*32 + ak];
      short8 al = *(const short8*)&xs[1][am][kt*32 + ak];
      #pragma unroll
      for(int ntl=0; ntl<8; ntl++){
        int g = ntb + ntl;
        short8 bh = Bh[(g*8 + kt)*64 + lane];
        short8 bl = Bl[(g*8 + kt)*64 + lane];
        acc[ntl] = __builtin_amdgcn_mfma_f32_16x16x32_bf16(ah, bh, acc[ntl], 0, 0, 0);
        acc[ntl] = __builtin_amdgcn_mfma_f32_16x16x32_bf16(ah, bl, acc[ntl], 0, 0, 0);
        acc[ntl] = __builtin_amdgcn_mfma_f32_16x16x32_bf16(al, bh, acc[ntl], 0, 0, 0);
      }
    }
  }
  __syncthreads();               // all layer-1 xs reads done
  // hidden: ReLU -> hi/lo bf16, overwrite xs
  #pragma unroll
  for(int ntl=0; ntl<8; ntl++){
    int col = (ntb + ntl)*16 + (lane & 15);
    int rowb = rt*16 + ((lane >> 4) << 2);
    #pragma unroll
    for(int reg=0; reg<4; reg++){
      float v = fmaxf(acc[ntl][reg], 0.f);
      unsigned short hi = f2b(v);
      xs[0][rowb + reg][col] = (short)hi;
      xs[1][rowb + reg][col] = (short)f2b(v - b2f(hi));
    }
  }
  __syncthreads();

  // layer 2: 256 -> 128
  const int ntb2 = (wv >> 1) * 4;
  f32x4 o4[4];
  #pragma unroll
  for(int ntl=0; ntl<4; ntl++){
    float bv = b2[(ntb2+ntl)*16 + (lane & 15)];
    o4[ntl] = (f32x4){bv, bv, bv, bv};
  }
  {
    const short8* Bh = (const short8*)W2h;
    const short8* Bl = (const short8*)W2l;
    #pragma unroll
    for(int kt=0; kt<8; kt++){
      short8 ah = *(const short8*)&xs[0][am][kt*32 + ak];
      short8 al = *(const short8*)&xs[1][am][kt*32 + ak];
      #pragma unroll
      for(int ntl=0; ntl<4; ntl++){
        int g = ntb2 + ntl;
        short8 bh = Bh[(g*8 + kt)*64 + lane];
        short8 bl = Bl[(g*8 + kt)*64 + lane];
        o4[ntl] = __builtin_amdgcn_mfma_f32_16x16x32_bf16(ah, bh, o4[ntl], 0, 0, 0);
        o4[ntl] = __builtin_amdgcn_mfma_f32_16x16x32_bf16(ah, bl, o4[ntl], 0, 0, 0);
        o4[ntl] = __builtin_amdgcn_mfma_f32_16x16x32_bf16(al, bh, o4[ntl], 0, 0, 0);
      }
    }
  }
  #pragma unroll
  for(int ntl=0; ntl<4; ntl++){
    int col = (ntb2 + ntl)*16 + (lane & 15);
    int rowb = r0 + rt*16 + ((lane >> 4) << 2);
    #pragma unroll
    for(int reg=0; reg<4; reg++)
      Y[(size_t)(rowb + reg)*128 + col] = o4[ntl][reg];
  }
}

// ---------------------------------------------------------------- col stats
__global__ __launch_bounds__(256) void k_colstats(const float* __restrict__ C, float* __restrict__ st){
  const int t = threadIdx.x, col = t & 127, h = t >> 7;
  float s = 0.f, s2 = 0.f;
  for(int r = blockIdx.x*2 + h; r < NCL; r += 1024){   // grid = 512 blocks
    float v = C[(size_t)r*128 + col];
    s += v; s2 += v*v;
  }
  __shared__ float red[256];
  red[t] = s; __syncthreads();
  if(t < 128) atomicAdd(&st[col], red[t] + red[t+128]);
  __syncthreads();
  red[t] = s2; __syncthreads();
  if(t < 128) atomicAdd(&st[128+col], red[t] + red[t+128]);
}

__global__ void k_finstats(float* st){
  int j = threadIdx.x;
  if(j < 128){
    const float n = (float)NCL;
    float mean = st[j]/n;
    float var = (st[128+j] - n*mean*mean) / (n - 1.f);   // ddof=1
    var = fmaxf(var, 0.f);
    st[256+j] = mean;
    st[384+j] = 1.f/(sqrtf(var) + 1e-10f);
  }
}

// -------- literal side: gather (analytically normalized) + MLP + res + LN
// 64 thr, 8 literals/block (R8-proven fp32 version).
__global__ __launch_bounds__(64) void k_lit_fused(
    const int* __restrict__ Pl, const int* __restrict__ lcl,
    const float* __restrict__ C, const float* __restrict__ st,
    const float* __restrict__ W1, const float* __restrict__ b1,
    const float* __restrict__ W2, const float* __restrict__ b2,
    const float* __restrict__ lng, const float* __restrict__ lnb, float* __restrict__ Lh){
  __shared__ float xs[8][132];
  __shared__ int rng[9];
  const int t = threadIdx.x;
  const int r0 = blockIdx.x * 8;

  if(t < 9) rng[t] = (r0 + t == 0) ? 0 : Pl[r0 + t - 1];
  __syncthreads();

  { const int half = t >> 5, f4 = (t & 31) * 4;
    float4 mean4 = *(const float4*)&st[256+f4];
    float4 isd4  = *(const float4*)&st[384+f4];
    for(int i=0;i<4;i++){
      int r = half*4 + i;
      int be = rng[r], en = rng[r+1];
      float4 a = make_float4(0.f,0.f,0.f,0.f);
      int c = (be < en) ? lcl[be] : 0;
      for(int e=be; e<en; e++){
        int cnext = (e+1 < en) ? lcl[e+1] : 0;
        float4 v = *(const float4*)&C[(size_t)c*128 + f4];
        a.x += v.x; a.y += v.y; a.z += v.z; a.w += v.w;
        c = cnext;
      }
      float dg = (float)(en - be);
      a.x = (a.x - dg*mean4.x)*isd4.x; a.y = (a.y - dg*mean4.y)*isd4.y;
      a.z = (a.z - dg*mean4.z)*isd4.z; a.w = (a.w - dg*mean4.w)*isd4.w;
      *(float4*)&xs[r][f4] = a;
    }
  }
  __syncthreads();

  const int c0 = (t & 15)*8, rb = (t >> 4)*2;
  float h[2][8];
  #pragma unroll
  for(int cc=0;cc<8;cc++){ float bv = b1[c0+cc]; h[0][cc]=bv; h[1][cc]=bv; }
  for(int k=0;k<128;k+=4){
    float4 xv[2];
    #pragma unroll
    for(int r=0;r<2;r++) xv[r] = *(const float4*)&xs[rb+r][k];
    #pragma unroll
    for(int kk=0;kk<4;kk++){
      float4 wa = *(const float4*)&W1[(size_t)(k+kk)*128 + c0];
      float4 wb = *(const float4*)&W1[(size_t)(k+kk)*128 + c0 + 4];
      #pragma unroll
      for(int r=0;r<2;r++){
        float x = (kk==0)?xv[r].x:(kk==1)?xv[r].y:(kk==2)?xv[r].z:xv[r].w;
        h[r][0]=fmaf(x,wa.x,h[r][0]); h[r][1]=fmaf(x,wa.y,h[r][1]);
        h[r][2]=fmaf(x,wa.z,h[r][2]); h[r][3]=fmaf(x,wa.w,h[r][3]);
        h[r][4]=fmaf(x,wb.x,h[r][4]); h[r][5]=fmaf(x,wb.y,h[r][5]);
        h[r][6]=fmaf(x,wb.z,h[r][6]); h[r][7]=fmaf(x,wb.w,h[r][7]);
      }
    }
  }
  __syncthreads();
  #pragma unroll
  for(int r=0;r<2;r++){
    *(float4*)&xs[rb+r][c0]   = make_float4(fmaxf(h[r][0],0.f),fmaxf(h[r][1],0.f),fmaxf(h[r][2],0.f),fmaxf(h[r][3],0.f));
    *(float4*)&xs[rb+r][c0+4] = make_float4(fmaxf(h[r][4],0.f),fmaxf(h[r][5],0.f),fmaxf(h[r][6],0.f),fmaxf(h[r][7],0.f));
  }
  __syncthreads();

  float y[2][8];
  #pragma unroll
  for(int cc=0;cc<8;cc++){ float bv = b2[c0+cc]; y[0][cc]=bv; y[1][cc]=bv; }
  for(int k=0;k<128;k+=4){
    float4 xv[2];
    #pragma unroll
    for(int r=0;r<2;r++) xv[r] = *(const float4*)&xs[rb+r][k];
    #pragma unroll
    for(int kk=0;kk<4;kk++){
      float4 wa = *(const float4*)&W2[(size_t)(k+kk)*128 + c0];
      float4 wb = *(const float4*)&W2[(size_t)(k+kk)*128 + c0 + 4];
      #pragma unroll
      for(int r=0;r<2;r++){
        float x = (kk==0)?xv[r].x:(kk==1)?xv[r].y:(kk==2)?xv[r].z:xv[r].w;
        y[r][0]=fmaf(x,wa.x,y[r][0]); y[r][1]=fmaf(x,wa.y,y[r][1]);
        y[r][2]=fmaf(x,wa.z,y[r][2]); y[r][3]=fmaf(x,wa.w,y[r][3]);
        y[r][4]=fmaf(x,wb.x,y[r][4]); y[r][5]=fmaf(x,wb.y,y[r][5]);
        y[r][6]=fmaf(x,wb.z,y[r][6]); y[r][7]=fmaf(x,wb.w,y[r][7]);
      }
    }
  }

  float gv[8], bv[8];
  #pragma unroll
  for(int cc=0;cc<8;cc++){ gv[cc]=lng[c0+cc]; bv[cc]=lnb[c0+cc]; }
  #pragma unroll
  for(int r=0;r<2;r++){
    size_t row = (size_t)(r0 + rb + r);
    float4 la = *(const float4*)&Lh[row*128 + c0];
    float4 lc = *(const float4*)&Lh[row*128 + c0 + 4];
    y[r][0] += 0.1f*la.x; y[r][1] += 0.1f*la.y; y[r][2] += 0.1f*la.z; y[r][3] += 0.1f*la.w;
    y[r][4] += 0.1f*lc.x; y[r][5] += 0.1f*lc.y; y[r][6] += 0.1f*lc.z; y[r][7] += 0.1f*lc.w;
    float s = 0.f, s2 = 0.f;
    #pragma unroll
    for(int cc=0;cc<8;cc++){ s += y[r][cc]; s2 += y[r][cc]*y[r][cc]; }
    #pragma unroll
    for(int m=1;m<16;m<<=1){ s += __shfl_xor(s,m,64); s2 += __shfl_xor(s2,m,64); }
    float mean = s*(1.f/128.f);
    float var  = s2*(1.f/128.f) - mean*mean;
    float rs   = rsqrtf(fmaxf(var, 0.f) + 1e-5f);
    float o[8];
    #pragma unroll
    for(int cc=0;cc<8;cc++) o[cc] = (y[r][cc]-mean)*rs*gv[cc] + bv[cc];
    *(float4*)&Lh[row*128 + c0]     = make_float4(o[0],o[1],o[2],o[3]);
    *(float4*)&Lh[row*128 + c0 + 4] = make_float4(o[4],o[5],o[6],o[7]);
  }
}

// ---------------------------------------------------------------- heads
__global__ __launch_bounds__(64) void k_head_v(const float* __restrict__ Lh,
    const float* __restrict__ W1d, const float* __restrict__ b1d, const float* __restrict__ W2d, const float* __restrict__ b2d,
    const float* __restrict__ W1c, const float* __restrict__ b1c, const float* __restrict__ W2c, const float* __restrict__ b2c,
    float* __restrict__ out){
  __shared__ float xs[8][256];
  const int t = threadIdx.x;
  const size_t v0 = (size_t)blockIdx.x * 8;
  #pragma unroll
  for(int r=0;r<8;r++){
    xs[r][t]     = Lh[(v0+r)*128 + t];
    xs[r][t+64]  = Lh[(v0+r)*128 + t + 64];
    xs[r][t+128] = Lh[(v0+r+HALFL)*128 + t];
    xs[r][t+192] = Lh[(v0+r+HALFL)*128 + t + 64];
  }
  __syncthreads();
  for(int hd=0; hd<2; hd++){
    const float* W1 = hd ? W1c : W1d;
    const float* b1 = hd ? b1c : b1d;
    const float* W2 = hd ? W2c : W2d;
    const float* b2 = hd ? b2c : b2d;
    float acc[8][4];
    #pragma unroll
    for(int c=0;c<4;c++){
      float bvv = b1[t + 64*c];
      #pragma unroll
      for(int r=0;r<8;r++) acc[r][c]=bvv;
    }
    for(int k=0;k<256;k+=4){
      float w[4][4];
      #pragma unroll
      for(int kk=0;kk<4;kk++)
        #pragma unroll
        for(int c=0;c<4;c++) w[kk][c] = W1[(size_t)(k+kk)*256 + t + 64*c];
      #pragma unroll
      for(int r=0;r<8;r++){
        float4 tv = *(const float4*)&xs[r][k];
        #pragma unroll
        for(int c=0;c<4;c++)
          acc[r][c] += tv.x*w[0][c] + tv.y*w[1][c] + tv.z*w[2][c] + tv.w*w[3][c];
      }
    }
    float w2[4];
    #pragma unroll
    for(int c=0;c<4;c++) w2[c] = W2[t + 64*c];
    float bb = b2[0];
    #pragma unroll
    for(int r=0;r<8;r++){
      float o = fmaxf(acc[r][0],0.f)*w2[0] + fmaxf(acc[r][1],0.f)*w2[1]
              + fmaxf(acc[r][2],0.f)*w2[2] + fmaxf(acc[r][3],0.f)*w2[3];
      #pragma unroll
      for(int m=1;m<64;m<<=1) o += __shfl_xor(o,m,64);
      if(t == 0) out[(size_t)hd*NVAR + v0 + r] = o + bb;
    }
  }
}

// 64 thr, 8 clauses/block; normalizes C on load.
__global__ __launch_bounds__(64) void k_head_c(const float* __restrict__ C,
    const float* __restrict__ st,
    const float* __restrict__ W1, const float* __restrict__ b1,
    const float* __restrict__ W2, const float* __restrict__ b2,
    float* __restrict__ out){
  __shared__ float xs[8][128];
  const int t = threadIdx.x;
  const size_t c0 = (size_t)blockIdx.x * 8;
  { float m0 = st[256+t], m1 = st[256+t+64];
    float i0 = st[384+t], i1 = st[384+t+64];
    #pragma unroll
    for(int r=0;r<8;r++){
      xs[r][t]    = (C[(c0+r)*128 + t]      - m0) * i0;
      xs[r][t+64] = (C[(c0+r)*128 + t + 64] - m1) * i1;
    }
  }
  __syncthreads();
  float a0[8], a1[8];
  float bv0 = b1[t], bv1 = b1[t+64];
  #pragma unroll
  for(int r=0;r<8;r++){ a0[r]=bv0; a1[r]=bv1; }
  for(int k=0;k<128;k+=4){
    float w0[4], w1[4];
    #pragma unroll
    for(int kk=0;kk<4;kk++){ w0[kk]=W1[(size_t)(k+kk)*128 + t]; w1[kk]=W1[(size_t)(k+kk)*128 + t + 64]; }
    #pragma unroll
    for(int r=0;r<8;r++){
      float4 tv = *(const float4*)&xs[r][k];
      a0[r] += tv.x*w0[0]+tv.y*w0[1]+tv.z*w0[2]+tv.w*w0[3];
      a1[r] += tv.x*w1[0]+tv.y*w1[1]+tv.z*w1[2]+tv.w*w1[3];
    }
  }
  float w2a = W2[t], w2b = W2[t+64];
  float bb = b2[0];
  #pragma unroll
  for(int r=0;r<8;r++){
    float o = fmaxf(a0[r],0.f)*w2a + fmaxf(a1[r],0.f)*w2b;
    #pragma unroll
    for(int m=1;m<64;m<<=1) o += __shfl_xor(o,m,64);
    if(t == 0) out[c0 + r] = o + bb;
  }
}

// ---------------------------------------------------------------- launch
extern "C" void kernel_launch(void* const* d_in, const int* in_sizes, int n_in,
                              void* d_out, int out_size, void* d_ws, size_t ws_size,
                              hipStream_t stream){
  const float* L0   = (const float*)d_in[0];
  const float* lng  = (const float*)d_in[1];
  const float* lnb  = (const float*)d_in[2];
  const float* CuW1 = (const float*)d_in[3];
  const float* Cub1 = (const float*)d_in[4];
  const float* CuW2 = (const float*)d_in[5];
  const float* Cub2 = (const float*)d_in[6];
  const float* LuW1 = (const float*)d_in[7];
  const float* Lub1 = (const float*)d_in[8];
  const float* LuW2 = (const float*)d_in[9];
  const float* Lub2 = (const float*)d_in[10];
  const float* VdW1 = (const float*)d_in[11];
  const float* Vdb1 = (const float*)d_in[12];
  const float* VdW2 = (const float*)d_in[13];
  const float* Vdb2 = (const float*)d_in[14];
  const float* VcW1 = (const float*)d_in[15];
  const float* Vcb1 = (const float*)d_in[16];
  const float* VcW2 = (const float*)d_in[17];
  const float* Vcb2 = (const float*)d_in[18];
  const float* CsW1 = (const float*)d_in[19];
  const float* Csb1 = (const float*)d_in[20];
  const float* CsW2 = (const float*)d_in[21];
  const float* Csb2 = (const float*)d_in[22];
  const int* cidx = (const int*)d_in[23];
  const int* lidx = (const int*)d_in[24];
  const int  ne   = in_sizes[23];

  float* ws   = (float*)d_ws;
  float* Lh   = ws;                        // 25,600,000 f32
  float* C    = ws + 25600000;             // 38,400,000 f32 -> end 64,000,000
  float* st   = ws + 64000000;             // 512: sum|sumsq|mean|isd
  short* W1h  = (short*)(ws + 64000512);   // 65,536 bf16
  short* W1l  = (short*)(ws + 64033280);   // 65,536 bf16
  short* W2h  = (short*)(ws + 64066048);   // 32,768 bf16
  short* W2l  = (short*)(ws + 64082432);   // 32,768 bf16
  int*   ib   = (int*)(ws + 64098816);     // int region
  int*   Pc   = ib;                        // PAD_C = 300,032
  int*   Pl   = ib + PAD_C;                // PAD_L = 200,704
  int*   clit = ib + PAD_C + PAD_L;        // 1,000,000
  int*   lcl  = clit + 1000000;            // 1,000,000
  int*   psum = lcl + 1000000;             // 512
  // total ws ~= 266.4 MB
  float* out = (float*)d_out;              // fp32: drat|core|c_core

  k_init_lh<<<100000, 256, 0, stream>>>(L0, Lh);
  k_pack_w<<<256, 256, 0, stream>>>(CuW1, W1h, W1l, 256, 256);
  k_pack_w<<<128, 256, 0, stream>>>(CuW2, W2h, W2l, 256, 128);

  // CSR build (counting sort both directions)
  k_zero4<<<489, 256, 0, stream>>>((float4*)Pc, (PAD_C + PAD_L)/4);
  k_hist<<<(ne+255)/256, 256, 0, stream>>>(cidx, lidx, Pc, Pl, ne);
  k_scan_pass1<<<NB_C, 256, 0, stream>>>(Pc, psum);
  k_scan_pass2<<<1, 512, 0, stream>>>(psum, NB_C);
  k_scan_pass3<<<NB_C, 256, 0, stream>>>(Pc, psum);
  k_scan_pass1<<<NB_L, 256, 0, stream>>>(Pl, psum);
  k_scan_pass2<<<1, 512, 0, stream>>>(psum, NB_L);
  k_scan_pass3<<<NB_L, 256, 0, stream>>>(Pl, psum);
  k_fill<<<(ne+255)/256, 256, 0, stream>>>(cidx, lidx, Pc, Pl, clit, lcl, ne);

  for(int hop=0; hop<4; hop++){
    k_zero4<<<1, 256, 0, stream>>>((float4*)st, 128);
    k_clause_fused<<<9375, 256, 0, stream>>>(Pc, clit, Lh, W1h, W1l, Cub1, W2h, W2l, Cub2, C);
    k_colstats<<<512, 256, 0, stream>>>(C, st);
    k_finstats<<<1, 128, 0, stream>>>(st);
    k_lit_fused<<<25000, 64, 0, stream>>>(Pl, lcl, C, st, LuW1, Lub1, LuW2, Lub2, lng, lnb, Lh);
  }
  k_head_v<<<12500, 64, 0, stream>>>(Lh, VdW1, Vdb1, VdW2, Vdb2, VcW1, Vcb1, VcW2, Vcb2, out);
  k_head_c<<<37500, 64, 0, stream>>>(C, st, CsW1, Csb1, CsW2, Csb2, out + 200000);
}

// Round 14
// 3646.730 us; speedup vs baseline: 2.6566x; 1.2589x over previous
//
#include <hip/hip_runtime.h>
#include <hip/hip_bf16.h>

#define NCL   300000
#define NLIT  200000
#define HALFL 100000
#define NVAR  100000

#define NB_C  293            // 293*1024 = 300032 >= NCL
#define PAD_C (NB_C*1024)
#define NB_L  196            // 196*1024 = 200704 >= NLIT
#define PAD_L (NB_L*1024)

typedef __attribute__((ext_vector_type(8))) short short8;   // 8 bf16 (4 VGPRs)
typedef __attribute__((ext_vector_type(4))) float f32x4;    // MFMA acc

__device__ __forceinline__ unsigned short f2b(float x){     // fp32 -> bf16 RNE
  union{float f; unsigned int u;} v; v.f = x;
  unsigned int r = v.u + 0x7FFF + ((v.u >> 16) & 1);
  return (unsigned short)(r >> 16);
}
__device__ __forceinline__ float b2f(unsigned short u){
  union{unsigned int i; float f;} x; x.i = ((unsigned int)u) << 16; return x.f;
}

// ---------------------------------------------------------------- utilities
__global__ void k_init_lh(const float* __restrict__ L0, float* __restrict__ Lh){
  int i = blockIdx.x*256 + threadIdx.x;            // 25,600,000 total
  Lh[i] = L0[i & 127];
}

__global__ void k_zero4(float4* __restrict__ p, int n4){
  int i = blockIdx.x*256 + threadIdx.x;
  if(i < n4) p[i] = make_float4(0.f,0.f,0.f,0.f);
}

// Pack fp32 row-major W[K][N] into hi/lo bf16 MFMA B-fragment order:
// frag[((nt*(K/32)+kt)*64 + lane)*8 + j] <- W[kt*32+(lane>>4)*8+j][nt*16+(lane&15)]
__global__ void k_pack_w(const float* __restrict__ W, short* __restrict__ Whi,
                         short* __restrict__ Wlo, int K, int N){
  int i = blockIdx.x*256 + threadIdx.x;
  if(i >= K*N) return;
  int j  = i & 7;
  int L  = (i >> 3) & 63;
  int kt = (i >> 9) % (K >> 5);
  int nt = (i >> 9) / (K >> 5);
  int k = kt*32 + ((L >> 4) << 3) + j;
  int n = nt*16 + (L & 15);
  float w = W[(size_t)k*N + n];
  unsigned short hi = f2b(w);
  Whi[i] = (short)hi;
  Wlo[i] = (short)f2b(w - b2f(hi));
}

// ---------------------------------------------------------------- CSR build
__global__ __launch_bounds__(256) void k_hist(const int* __restrict__ ci, const int* __restrict__ li,
    int* __restrict__ Pc, int* __restrict__ Pl, int ne){
  int e = blockIdx.x*256 + threadIdx.x;
  if(e < ne){ atomicAdd(&Pc[ci[e]], 1); atomicAdd(&Pl[li[e]], 1); }
}

__global__ __launch_bounds__(256) void k_scan_pass1(const int* __restrict__ P, int* __restrict__ psum){
  __shared__ int red[256];
  int t = threadIdx.x;
  int4 v = *(const int4*)&P[blockIdx.x*1024 + t*4];
  red[t] = v.x + v.y + v.z + v.w;
  __syncthreads();
  for(int ofs=128; ofs>0; ofs>>=1){
    if(t < ofs) red[t] += red[t+ofs];
    __syncthreads();
  }
  if(t == 0) psum[blockIdx.x] = red[0];
}

__global__ __launch_bounds__(512) void k_scan_pass2(int* __restrict__ psum, int nb){
  __shared__ int sA[512], sB[512];
  int t = threadIdx.x;
  sA[t] = (t < nb) ? psum[t] : 0;
  __syncthreads();
  int* src = sA; int* dst = sB;
  for(int ofs=1; ofs<512; ofs<<=1){
    int x = src[t];
    if(t >= ofs) x += src[t-ofs];
    dst[t] = x;
    __syncthreads();
    int* tmp = src; src = dst; dst = tmp;
  }
  psum[t] = t ? src[t-1] : 0;    // exclusive
}

__global__ __launch_bounds__(256) void k_scan_pass3(int* __restrict__ P, const int* __restrict__ psum){
  __shared__ int sA[256], sB[256];
  int t = threadIdx.x;
  int base = blockIdx.x*1024 + t*4;
  int4 v = *(const int4*)&P[base];
  int tsum = v.x + v.y + v.z + v.w;
  sA[t] = tsum;
  __syncthreads();
  int* src = sA; int* dst = sB;
  for(int ofs=1; ofs<256; ofs<<=1){
    int x = src[t];
    if(t >= ofs) x += src[t-ofs];
    dst[t] = x;
    __syncthreads();
    int* tmp = src; src = dst; dst = tmp;
  }
  int excl = psum[blockIdx.x] + src[t] - tsum;   // exclusive across whole array
  int4 o;
  o.x = excl;
  o.y = o.x + v.x;
  o.z = o.y + v.y;
  o.w = o.z + v.z;
  *(int4*)&P[base] = o;
}

// After k_fill, P[c] holds END offset of row c; begin(c) = c ? P[c-1] : 0.
__global__ __launch_bounds__(256) void k_fill(const int* __restrict__ ci, const int* __restrict__ li,
    int* __restrict__ Pc, int* __restrict__ Pl, int* __restrict__ clit, int* __restrict__ lcl, int ne){
  int e = blockIdx.x*256 + threadIdx.x;
  if(e < ne){
    int c = ci[e], l = li[e];
    clit[atomicAdd(&Pc[c], 1)] = l;
    lcl [atomicAdd(&Pl[l], 1)] = c;
  }
}

// ------ clause side: CSR gather + COMPENSATED bf16 MFMA MLP 256->256->128
// (R13-proven). 256 thr, 32 clauses/block, xs[2][32][264] hi/lo planes.
__global__ __launch_bounds__(256) void k_clause_fused(
    const int* __restrict__ Pc, const int* __restrict__ clit,
    const float* __restrict__ Lh,
    const short* __restrict__ W1h, const short* __restrict__ W1l, const float* __restrict__ b1,
    const short* __restrict__ W2h, const short* __restrict__ W2l, const float* __restrict__ b2,
    float* __restrict__ Y){
  __shared__ short xs[2][32][264];
  __shared__ int rng[33];
  const int t = threadIdx.x;
  const int r0 = blockIdx.x * 32;

  if(t < 33) rng[t] = (r0 + t == 0) ? 0 : Pc[r0 + t - 1];
  __syncthreads();

  const int lane = t & 63, wv = t >> 6;
  { // gather: wave wv rows wv*8..+7; lanes 0-31 direct, 32-63 flipped; f4/lane
    const int half = lane >> 5, f4 = (lane & 31) * 4;
    for(int i=0;i<8;i++){
      int r = wv*8 + i;
      int be = rng[r], en = rng[r+1];
      float4 a = make_float4(0.f,0.f,0.f,0.f);
      int l = (be < en) ? clit[be] : 0;
      for(int e=be; e<en; e++){
        int lnext = (e+1 < en) ? clit[e+1] : 0;          // prefetch next index
        int src = half ? ((l < HALFL) ? l + HALFL : l - HALFL) : l;
        float4 v = *(const float4*)&Lh[(size_t)src*128 + f4];
        a.x += v.x; a.y += v.y; a.z += v.z; a.w += v.w;
        l = lnext;
      }
      unsigned short hx=f2b(a.x), hy=f2b(a.y), hz=f2b(a.z), hw=f2b(a.w);
      unsigned short lx=f2b(a.x-b2f(hx)), ly=f2b(a.y-b2f(hy));
      unsigned short lz=f2b(a.z-b2f(hz)), lw=f2b(a.w-b2f(hw));
      *(uint2*)&xs[0][r][half*128 + f4] =
        make_uint2(((unsigned int)hy<<16)|hx, ((unsigned int)hw<<16)|hz);
      *(uint2*)&xs[1][r][half*128 + f4] =
        make_uint2(((unsigned int)ly<<16)|lx, ((unsigned int)lw<<16)|lz);
    }
  }
  __syncthreads();

  const int rt  = wv & 1;
  const int ntb = (wv >> 1) * 8;
  const int am  = rt*16 + (lane & 15);
  const int ak  = (lane >> 4) * 8;

  // layer 1: 256 -> 256
  f32x4 acc[8];
  #pragma unroll
  for(int ntl=0; ntl<8; ntl++){
    float bv = b1[(ntb+ntl)*16 + (lane & 15)];
    acc[ntl] = (f32x4){bv, bv, bv, bv};
  }
  {
    const short8* Bh = (const short8*)W1h;
    const short8* Bl = (const short8*)W1l;
    #pragma unroll
    for(int kt=0; kt<8; kt++){
      short8 ah = *(const short8*)&xs[0][am][kt*32 + ak];
      short8 al = *(const short8*)&xs[1][am][kt*32 + ak];
      #pragma unroll
      for(int ntl=0; ntl<8; ntl++){
        int g = ntb + ntl;
        short8 bh = Bh[(g*8 + kt)*64 + lane];
        short8 bl = Bl[(g*8 + kt)*64 + lane];
        acc[ntl] = __builtin_amdgcn_mfma_f32_16x16x32_bf16(ah, bh, acc[ntl], 0, 0, 0);
        acc[ntl] = __builtin_amdgcn_mfma_f32_16x16x32_bf16(ah, bl, acc[ntl], 0, 0, 0);
        acc[ntl] = __builtin_amdgcn_mfma_f32_16x16x32_bf16(al, bh, acc[ntl], 0, 0, 0);
      }
    }
  }
  __syncthreads();
  #pragma unroll
  for(int ntl=0; ntl<8; ntl++){
    int col = (ntb + ntl)*16 + (lane & 15);
    int rowb = rt*16 + ((lane >> 4) << 2);
    #pragma unroll
    for(int reg=0; reg<4; reg++){
      float v = fmaxf(acc[ntl][reg], 0.f);
      unsigned short hi = f2b(v);
      xs[0][rowb + reg][col] = (short)hi;
      xs[1][rowb + reg][col] = (short)f2b(v - b2f(hi));
    }
  }
  __syncthreads();

  // layer 2: 256 -> 128
  const int ntb2 = (wv >> 1) * 4;
  f32x4 o4[4];
  #pragma unroll
  for(int ntl=0; ntl<4; ntl++){
    float bv = b2[(ntb2+ntl)*16 + (lane & 15)];
    o4[ntl] = (f32x4){bv, bv, bv, bv};
  }
  {
    const short8* Bh = (const short8*)W2h;
    const short8* Bl = (const short8*)W2l;
    #pragma unroll
    for(int kt=0; kt<8; kt++){
      short8 ah = *(const short8*)&xs[0][am][kt*32 + ak];
      short8 al = *(const short8*)&xs[1][am][kt*32 + ak];
      #pragma unroll
      for(int ntl=0; ntl<4; ntl++){
        int g = ntb2 + ntl;
        short8 bh = Bh[(g*8 + kt)*64 + lane];
        short8 bl = Bl[(g*8 + kt)*64 + lane];
        o4[ntl] = __builtin_amdgcn_mfma_f32_16x16x32_bf16(ah, bh, o4[ntl], 0, 0, 0);
        o4[ntl] = __builtin_amdgcn_mfma_f32_16x16x32_bf16(ah, bl, o4[ntl], 0, 0, 0);
        o4[ntl] = __builtin_amdgcn_mfma_f32_16x16x32_bf16(al, bh, o4[ntl], 0, 0, 0);
      }
    }
  }
  #pragma unroll
  for(int ntl=0; ntl<4; ntl++){
    int col = (ntb2 + ntl)*16 + (lane & 15);
    int rowb = r0 + rt*16 + ((lane >> 4) << 2);
    #pragma unroll
    for(int reg=0; reg<4; reg++)
      Y[(size_t)(rowb + reg)*128 + col] = o4[ntl][reg];
  }
}

// ---------------------------------------------------------------- col stats
__global__ __launch_bounds__(256) void k_colstats(const float* __restrict__ C, float* __restrict__ st){
  const int t = threadIdx.x, col = t & 127, h = t >> 7;
  float s = 0.f, s2 = 0.f;
  for(int r = blockIdx.x*2 + h; r < NCL; r += 1024){   // grid = 512 blocks
    float v = C[(size_t)r*128 + col];
    s += v; s2 += v*v;
  }
  __shared__ float red[256];
  red[t] = s; __syncthreads();
  if(t < 128) atomicAdd(&st[col], red[t] + red[t+128]);
  __syncthreads();
  red[t] = s2; __syncthreads();
  if(t < 128) atomicAdd(&st[128+col], red[t] + red[t+128]);
}

__global__ void k_finstats(float* st){
  int j = threadIdx.x;
  if(j < 128){
    const float n = (float)NCL;
    float mean = st[j]/n;
    float var = (st[128+j] - n*mean*mean) / (n - 1.f);   // ddof=1
    var = fmaxf(var, 0.f);
    st[256+j] = mean;
    st[384+j] = 1.f/(sqrtf(var) + 1e-10f);
  }
}

// -- literal side: gather(normalized) + COMPENSATED bf16 MFMA 128->128->128
//    + 0.1*residual + LayerNorm. 256 thr, 32 lits/block.
// LDS: xs[2][32][136] bf16 hi/lo (17.4 KB); layer-2 output returns through
// the same LDS reinterpreted as float ys[32][132] (16.9 KB) for the LN.
__global__ __launch_bounds__(256) void k_lit_fused(
    const int* __restrict__ Pl, const int* __restrict__ lcl,
    const float* __restrict__ C, const float* __restrict__ st,
    const short* __restrict__ W1h, const short* __restrict__ W1l, const float* __restrict__ b1,
    const short* __restrict__ W2h, const short* __restrict__ W2l, const float* __restrict__ b2,
    const float* __restrict__ lng, const float* __restrict__ lnb, float* __restrict__ Lh){
  __shared__ short xs[2][32][136];
  __shared__ int rng[33];
  float* ys = (float*)&xs[0][0][0];          // [32][132] fp32, aliases xs
  const int t = threadIdx.x;
  const int r0 = blockIdx.x * 32;

  if(t < 33) rng[t] = (r0 + t == 0) ? 0 : Pl[r0 + t - 1];
  __syncthreads();

  const int lane = t & 63, wv = t >> 6;
  { // gather: wave wv rows wv*8..+7 (half-wave 4 rows each); f4/lane covers 128
    const int half = lane >> 5, f4 = (lane & 31) * 4;
    float4 mean4 = *(const float4*)&st[256+f4];
    float4 isd4  = *(const float4*)&st[384+f4];
    for(int i=0;i<4;i++){
      int r = wv*8 + half*4 + i;
      int be = rng[r], en = rng[r+1];
      float4 a = make_float4(0.f,0.f,0.f,0.f);
      int c = (be < en) ? lcl[be] : 0;
      for(int e=be; e<en; e++){
        int cnext = (e+1 < en) ? lcl[e+1] : 0;
        float4 v = *(const float4*)&C[(size_t)c*128 + f4];
        a.x += v.x; a.y += v.y; a.z += v.z; a.w += v.w;
        c = cnext;
      }
      float dg = (float)(en - be);
      a.x = (a.x - dg*mean4.x)*isd4.x; a.y = (a.y - dg*mean4.y)*isd4.y;
      a.z = (a.z - dg*mean4.z)*isd4.z; a.w = (a.w - dg*mean4.w)*isd4.w;
      unsigned short hx=f2b(a.x), hy=f2b(a.y), hz=f2b(a.z), hw=f2b(a.w);
      unsigned short lx=f2b(a.x-b2f(hx)), ly=f2b(a.y-b2f(hy));
      unsigned short lz=f2b(a.z-b2f(hz)), lw=f2b(a.w-b2f(hw));
      *(uint2*)&xs[0][r][f4] = make_uint2(((unsigned int)hy<<16)|hx, ((unsigned int)hw<<16)|hz);
      *(uint2*)&xs[1][r][f4] = make_uint2(((unsigned int)ly<<16)|lx, ((unsigned int)lw<<16)|lz);
    }
  }
  __syncthreads();

  const int rt  = wv & 1;                 // row-tile (rows rt*16..+15)
  const int ntb = (wv >> 1) * 4;          // 4 n-tiles per wave-pair (128 cols)
  const int am  = rt*16 + (lane & 15);
  const int ak  = (lane >> 4) * 8;

  // layer 1: 128 -> 128 (kt in 0..3)
  f32x4 acc[4];
  #pragma unroll
  for(int ntl=0; ntl<4; ntl++){
    float bv = b1[(ntb+ntl)*16 + (lane & 15)];
    acc[ntl] = (f32x4){bv, bv, bv, bv};
  }
  {
    const short8* Bh = (const short8*)W1h;
    const short8* Bl = (const short8*)W1l;
    #pragma unroll
    for(int kt=0; kt<4; kt++){
      short8 ah = *(const short8*)&xs[0][am][kt*32 + ak];
      short8 al = *(const short8*)&xs[1][am][kt*32 + ak];
      #pragma unroll
      for(int ntl=0; ntl<4; ntl++){
        int g = ntb + ntl;
        short8 bh = Bh[(g*4 + kt)*64 + lane];
        short8 bl = Bl[(g*4 + kt)*64 + lane];
        acc[ntl] = __builtin_amdgcn_mfma_f32_16x16x32_bf16(ah, bh, acc[ntl], 0, 0, 0);
        acc[ntl] = __builtin_amdgcn_mfma_f32_16x16x32_bf16(ah, bl, acc[ntl], 0, 0, 0);
        acc[ntl] = __builtin_amdgcn_mfma_f32_16x16x32_bf16(al, bh, acc[ntl], 0, 0, 0);
      }
    }
  }
  __syncthreads();
  // hidden: ReLU -> hi/lo bf16, overwrite xs
  #pragma unroll
  for(int ntl=0; ntl<4; ntl++){
    int col = (ntb + ntl)*16 + (lane & 15);
    int rowb = rt*16 + ((lane >> 4) << 2);
    #pragma unroll
    for(int reg=0; reg<4; reg++){
      float v = fmaxf(acc[ntl][reg], 0.f);
      unsigned short hi = f2b(v);
      xs[0][rowb + reg][col] = (short)hi;
      xs[1][rowb + reg][col] = (short)f2b(v - b2f(hi));
    }
  }
  __syncthreads();

  // layer 2: 128 -> 128 (A-frags loaded upfront, then xs is reused as ys)
  short8 a2h[4], a2l[4];
  #pragma unroll
  for(int kt=0; kt<4; kt++){
    a2h[kt] = *(const short8*)&xs[0][am][kt*32 + ak];
    a2l[kt] = *(const short8*)&xs[1][am][kt*32 + ak];
  }
  __syncthreads();                         // all xs reads done -> ys writable
  f32x4 o4[4];
  #pragma unroll
  for(int ntl=0; ntl<4; ntl++){
    float bv = b2[(ntb+ntl)*16 + (lane & 15)];
    o4[ntl] = (f32x4){bv, bv, bv, bv};
  }
  {
    const short8* Bh = (const short8*)W2h;
    const short8* Bl = (const short8*)W2l;
    #pragma unroll
    for(int kt=0; kt<4; kt++){
      #pragma unroll
      for(int ntl=0; ntl<4; ntl++){
        int g = ntb + ntl;
        short8 bh = Bh[(g*4 + kt)*64 + lane];
        short8 bl = Bl[(g*4 + kt)*64 + lane];
        o4[ntl] = __builtin_amdgcn_mfma_f32_16x16x32_bf16(a2h[kt], bh, o4[ntl], 0, 0, 0);
        o4[ntl] = __builtin_amdgcn_mfma_f32_16x16x32_bf16(a2h[kt], bl, o4[ntl], 0, 0, 0);
        o4[ntl] = __builtin_amdgcn_mfma_f32_16x16x32_bf16(a2l[kt], bh, o4[ntl], 0, 0, 0);
      }
    }
  }
  #pragma unroll
  for(int ntl=0; ntl<4; ntl++){
    int col = (ntb + ntl)*16 + (lane & 15);
    int rowb = rt*16 + ((lane >> 4) << 2);
    #pragma unroll
    for(int reg=0; reg<4; reg++)
      ys[(rowb + reg)*132 + col] = o4[ntl][reg];
  }
  __syncthreads();

  { // residual + LayerNorm: 8 threads per row, 16 cols each
    const int r  = t >> 3;                 // 0..31
    const int cg = (t & 7) * 16;
    size_t row = (size_t)(r0 + r);
    float y[16];
    #pragma unroll
    for(int jj=0; jj<16; jj+=4){
      float4 v = *(const float4*)&ys[r*132 + cg + jj];
      float4 la = *(const float4*)&Lh[row*128 + cg + jj];
      y[jj]   = v.x + 0.1f*la.x; y[jj+1] = v.y + 0.1f*la.y;
      y[jj+2] = v.z + 0.1f*la.z; y[jj+3] = v.w + 0.1f*la.w;
    }
    float s = 0.f, s2 = 0.f;
    #pragma unroll
    for(int jj=0; jj<16; jj++){ s += y[jj]; s2 += y[jj]*y[jj]; }
    #pragma unroll
    for(int m=1; m<8; m<<=1){ s += __shfl_xor(s,m,64); s2 += __shfl_xor(s2,m,64); }
    float mean = s*(1.f/128.f);
    float var  = s2*(1.f/128.f) - mean*mean;
    float rs   = rsqrtf(fmaxf(var, 0.f) + 1e-5f);
    #pragma unroll
    for(int jj=0; jj<16; jj+=4){
      float4 gv = *(const float4*)&lng[cg + jj];
      float4 bv = *(const float4*)&lnb[cg + jj];
      *(float4*)&Lh[row*128 + cg + jj] = make_float4(
        (y[jj]  -mean)*rs*gv.x + bv.x, (y[jj+1]-mean)*rs*gv.y + bv.y,
        (y[jj+2]-mean)*rs*gv.z + bv.z, (y[jj+3]-mean)*rs*gv.w + bv.w);
    }
  }
}

// ---------------------------------------------------------------- heads
__global__ __launch_bounds__(64) void k_head_v(const float* __restrict__ Lh,
    const float* __restrict__ W1d, const float* __restrict__ b1d, const float* __restrict__ W2d, const float* __restrict__ b2d,
    const float* __restrict__ W1c, const float* __restrict__ b1c, const float* __restrict__ W2c, const float* __restrict__ b2c,
    float* __restrict__ out){
  __shared__ float xs[8][256];
  const int t = threadIdx.x;
  const size_t v0 = (size_t)blockIdx.x * 8;
  #pragma unroll
  for(int r=0;r<8;r++){
    xs[r][t]     = Lh[(v0+r)*128 + t];
    xs[r][t+64]  = Lh[(v0+r)*128 + t + 64];
    xs[r][t+128] = Lh[(v0+r+HALFL)*128 + t];
    xs[r][t+192] = Lh[(v0+r+HALFL)*128 + t + 64];
  }
  __syncthreads();
  for(int hd=0; hd<2; hd++){
    const float* W1 = hd ? W1c : W1d;
    const float* b1 = hd ? b1c : b1d;
    const float* W2 = hd ? W2c : W2d;
    const float* b2 = hd ? b2c : b2d;
    float acc[8][4];
    #pragma unroll
    for(int c=0;c<4;c++){
      float bvv = b1[t + 64*c];
      #pragma unroll
      for(int r=0;r<8;r++) acc[r][c]=bvv;
    }
    for(int k=0;k<256;k+=4){
      float w[4][4];
      #pragma unroll
      for(int kk=0;kk<4;kk++)
        #pragma unroll
        for(int c=0;c<4;c++) w[kk][c] = W1[(size_t)(k+kk)*256 + t + 64*c];
      #pragma unroll
      for(int r=0;r<8;r++){
        float4 tv = *(const float4*)&xs[r][k];
        #pragma unroll
        for(int c=0;c<4;c++)
          acc[r][c] += tv.x*w[0][c] + tv.y*w[1][c] + tv.z*w[2][c] + tv.w*w[3][c];
      }
    }
    float w2[4];
    #pragma unroll
    for(int c=0;c<4;c++) w2[c] = W2[t + 64*c];
    float bb = b2[0];
    #pragma unroll
    for(int r=0;r<8;r++){
      float o = fmaxf(acc[r][0],0.f)*w2[0] + fmaxf(acc[r][1],0.f)*w2[1]
              + fmaxf(acc[r][2],0.f)*w2[2] + fmaxf(acc[r][3],0.f)*w2[3];
      #pragma unroll
      for(int m=1;m<64;m<<=1) o += __shfl_xor(o,m,64);
      if(t == 0) out[(size_t)hd*NVAR + v0 + r] = o + bb;
    }
  }
}

// 64 thr, 8 clauses/block; normalizes C on load.
__global__ __launch_bounds__(64) void k_head_c(const float* __restrict__ C,
    const float* __restrict__ st,
    const float* __restrict__ W1, const float* __restrict__ b1,
    const float* __restrict__ W2, const float* __restrict__ b2,
    float* __restrict__ out){
  __shared__ float xs[8][128];
  const int t = threadIdx.x;
  const size_t c0 = (size_t)blockIdx.x * 8;
  { float m0 = st[256+t], m1 = st[256+t+64];
    float i0 = st[384+t], i1 = st[384+t+64];
    #pragma unroll
    for(int r=0;r<8;r++){
      xs[r][t]    = (C[(c0+r)*128 + t]      - m0) * i0;
      xs[r][t+64] = (C[(c0+r)*128 + t + 64] - m1) * i1;
    }
  }
  __syncthreads();
  float a0[8], a1[8];
  float bv0 = b1[t], bv1 = b1[t+64];
  #pragma unroll
  for(int r=0;r<8;r++){ a0[r]=bv0; a1[r]=bv1; }
  for(int k=0;k<128;k+=4){
    float w0[4], w1[4];
    #pragma unroll
    for(int kk=0;kk<4;kk++){ w0[kk]=W1[(size_t)(k+kk)*128 + t]; w1[kk]=W1[(size_t)(k+kk)*128 + t + 64]; }
    #pragma unroll
    for(int r=0;r<8;r++){
      float4 tv = *(const float4*)&xs[r][k];
      a0[r] += tv.x*w0[0]+tv.y*w0[1]+tv.z*w0[2]+tv.w*w0[3];
      a1[r] += tv.x*w1[0]+tv.y*w1[1]+tv.z*w1[2]+tv.w*w1[3];
    }
  }
  float w2a = W2[t], w2b = W2[t+64];
  float bb = b2[0];
  #pragma unroll
  for(int r=0;r<8;r++){
    float o = fmaxf(a0[r],0.f)*w2a + fmaxf(a1[r],0.f)*w2b;
    #pragma unroll
    for(int m=1;m<64;m<<=1) o += __shfl_xor(o,m,64);
    if(t == 0) out[c0 + r] = o + bb;
  }
}

// ---------------------------------------------------------------- launch
extern "C" void kernel_launch(void* const* d_in, const int* in_sizes, int n_in,
                              void* d_out, int out_size, void* d_ws, size_t ws_size,
                              hipStream_t stream){
  const float* L0   = (const float*)d_in[0];
  const float* lng  = (const float*)d_in[1];
  const float* lnb  = (const float*)d_in[2];
  const float* CuW1 = (const float*)d_in[3];
  const float* Cub1 = (const float*)d_in[4];
  const float* CuW2 = (const float*)d_in[5];
  const float* Cub2 = (const float*)d_in[6];
  const float* LuW1 = (const float*)d_in[7];
  const float* Lub1 = (const float*)d_in[8];
  const float* LuW2 = (const float*)d_in[9];
  const float* Lub2 = (const float*)d_in[10];
  const float* VdW1 = (const float*)d_in[11];
  const float* Vdb1 = (const float*)d_in[12];
  const float* VdW2 = (const float*)d_in[13];
  const float* Vdb2 = (const float*)d_in[14];
  const float* VcW1 = (const float*)d_in[15];
  const float* Vcb1 = (const float*)d_in[16];
  const float* VcW2 = (const float*)d_in[17];
  const float* Vcb2 = (const float*)d_in[18];
  const float* CsW1 = (const float*)d_in[19];
  const float* Csb1 = (const float*)d_in[20];
  const float* CsW2 = (const float*)d_in[21];
  const float* Csb2 = (const float*)d_in[22];
  const int* cidx = (const int*)d_in[23];
  const int* lidx = (const int*)d_in[24];
  const int  ne   = in_sizes[23];

  float* ws   = (float*)d_ws;
  float* Lh   = ws;                        // 25,600,000 f32
  float* C    = ws + 25600000;             // 38,400,000 f32 -> end 64,000,000
  float* st   = ws + 64000000;             // 512: sum|sumsq|mean|isd
  short* W1h  = (short*)(ws + 64000512);   // 65,536 bf16
  short* W1l  = (short*)(ws + 64033280);   // 65,536 bf16
  short* W2h  = (short*)(ws + 64066048);   // 32,768 bf16
  short* W2l  = (short*)(ws + 64082432);   // 32,768 bf16
  short* W3h  = (short*)(ws + 64098816);   // 16,384 bf16 (LuW1 hi)
  short* W3l  = (short*)(ws + 64107008);   // 16,384 bf16
  short* W4h  = (short*)(ws + 64115200);   // 16,384 bf16 (LuW2 hi)
  short* W4l  = (short*)(ws + 64123392);   // 16,384 bf16
  int*   ib   = (int*)(ws + 64131584);     // int region
  int*   Pc   = ib;                        // PAD_C = 300,032
  int*   Pl   = ib + PAD_C;                // PAD_L = 200,704
  int*   clit = ib + PAD_C + PAD_L;        // 1,000,000
  int*   lcl  = clit + 1000000;            // 1,000,000
  int*   psum = lcl + 1000000;             // 512
  // total ws ~= 266.6 MB
  float* out = (float*)d_out;              // fp32: drat|core|c_core

  k_init_lh<<<100000, 256, 0, stream>>>(L0, Lh);
  k_pack_w<<<256, 256, 0, stream>>>(CuW1, W1h, W1l, 256, 256);
  k_pack_w<<<128, 256, 0, stream>>>(CuW2, W2h, W2l, 256, 128);
  k_pack_w<<<64, 256, 0, stream>>>(LuW1, W3h, W3l, 128, 128);
  k_pack_w<<<64, 256, 0, stream>>>(LuW2, W4h, W4l, 128, 128);

  // CSR build (counting sort both directions)
  k_zero4<<<489, 256, 0, stream>>>((float4*)Pc, (PAD_C + PAD_L)/4);
  k_hist<<<(ne+255)/256, 256, 0, stream>>>(cidx, lidx, Pc, Pl, ne);
  k_scan_pass1<<<NB_C, 256, 0, stream>>>(Pc, psum);
  k_scan_pass2<<<1, 512, 0, stream>>>(psum, NB_C);
  k_scan_pass3<<<NB_C, 256, 0, stream>>>(Pc, psum);
  k_scan_pass1<<<NB_L, 256, 0, stream>>>(Pl, psum);
  k_scan_pass2<<<1, 512, 0, stream>>>(psum, NB_L);
  k_scan_pass3<<<NB_L, 256, 0, stream>>>(Pl, psum);
  k_fill<<<(ne+255)/256, 256, 0, stream>>>(cidx, lidx, Pc, Pl, clit, lcl, ne);

  for(int hop=0; hop<4; hop++){
    k_zero4<<<1, 256, 0, stream>>>((float4*)st, 128);
    k_clause_fused<<<9375, 256, 0, stream>>>(Pc, clit, Lh, W1h, W1l, Cub1, W2h, W2l, Cub2, C);
    k_colstats<<<512, 256, 0, stream>>>(C, st);
    k_finstats<<<1, 128, 0, stream>>>(st);
    k_lit_fused<<<6250, 256, 0, stream>>>(Pl, lcl, C, st, W3h, W3l, Lub1, W4h, W4l, Lub2, lng, lnb, Lh);
  }
  k_head_v<<<12500, 64, 0, stream>>>(Lh, VdW1, Vdb1, VdW2, Vdb2, VcW1, Vcb1, VcW2, Vcb2, out);
  k_head_c<<<37500, 64, 0, stream>>>(C, st, CsW1, Csb1, CsW2, Csb2, out + 200000);
}

// Round 15
// 3287.151 us; speedup vs baseline: 2.9472x; 1.1094x over previous
//
#include <hip/hip_runtime.h>
#include <hip/hip_bf16.h>

#define NCL   300000
#define NLIT  200000
#define HALFL 100000
#define NVAR  100000

#define NB_C  293            // 293*1024 = 300032 >= NCL
#define PAD_C (NB_C*1024)
#define NB_L  196            // 196*1024 = 200704 >= NLIT
#define PAD_L (NB_L*1024)

typedef __attribute__((ext_vector_type(8))) short short8;   // 8 bf16 (4 VGPRs)
typedef __attribute__((ext_vector_type(4))) float f32x4;    // MFMA acc

__device__ __forceinline__ unsigned short f2b(float x){     // fp32 -> bf16 RNE
  union{float f; unsigned int u;} v; v.f = x;
  unsigned int r = v.u + 0x7FFF + ((v.u >> 16) & 1);
  return (unsigned short)(r >> 16);
}
__device__ __forceinline__ float b2f(unsigned short u){
  union{unsigned int i; float f;} x; x.i = ((unsigned int)u) << 16; return x.f;
}
__device__ __forceinline__ int imax(int a, int b){ return a > b ? a : b; }

// ---------------------------------------------------------------- utilities
__global__ void k_init_lh(const float* __restrict__ L0, float* __restrict__ Lh){
  int i = blockIdx.x*256 + threadIdx.x;            // 25,600,000 total
  Lh[i] = L0[i & 127];
}

__global__ void k_zero4(float4* __restrict__ p, int n4){
  int i = blockIdx.x*256 + threadIdx.x;
  if(i < n4) p[i] = make_float4(0.f,0.f,0.f,0.f);
}

// Pack fp32 row-major W[K][N] into hi/lo bf16 MFMA B-fragment order:
// frag[((nt*(K/32)+kt)*64 + lane)*8 + j] <- W[kt*32+(lane>>4)*8+j][nt*16+(lane&15)]
__global__ void k_pack_w(const float* __restrict__ W, short* __restrict__ Whi,
                         short* __restrict__ Wlo, int K, int N){
  int i = blockIdx.x*256 + threadIdx.x;
  if(i >= K*N) return;
  int j  = i & 7;
  int L  = (i >> 3) & 63;
  int kt = (i >> 9) % (K >> 5);
  int nt = (i >> 9) / (K >> 5);
  int k = kt*32 + ((L >> 4) << 3) + j;
  int n = nt*16 + (L & 15);
  float w = W[(size_t)k*N + n];
  unsigned short hi = f2b(w);
  Whi[i] = (short)hi;
  Wlo[i] = (short)f2b(w - b2f(hi));
}

// ---------------------------------------------------------------- CSR build
__global__ __launch_bounds__(256) void k_hist(const int* __restrict__ ci, const int* __restrict__ li,
    int* __restrict__ Pc, int* __restrict__ Pl, int ne){
  int e = blockIdx.x*256 + threadIdx.x;
  if(e < ne){ atomicAdd(&Pc[ci[e]], 1); atomicAdd(&Pl[li[e]], 1); }
}

__global__ __launch_bounds__(256) void k_scan_pass1(const int* __restrict__ P, int* __restrict__ psum){
  __shared__ int red[256];
  int t = threadIdx.x;
  int4 v = *(const int4*)&P[blockIdx.x*1024 + t*4];
  red[t] = v.x + v.y + v.z + v.w;
  __syncthreads();
  for(int ofs=128; ofs>0; ofs>>=1){
    if(t < ofs) red[t] += red[t+ofs];
    __syncthreads();
  }
  if(t == 0) psum[blockIdx.x] = red[0];
}

__global__ __launch_bounds__(512) void k_scan_pass2(int* __restrict__ psum, int nb){
  __shared__ int sA[512], sB[512];
  int t = threadIdx.x;
  sA[t] = (t < nb) ? psum[t] : 0;
  __syncthreads();
  int* src = sA; int* dst = sB;
  for(int ofs=1; ofs<512; ofs<<=1){
    int x = src[t];
    if(t >= ofs) x += src[t-ofs];
    dst[t] = x;
    __syncthreads();
    int* tmp = src; src = dst; dst = tmp;
  }
  psum[t] = t ? src[t-1] : 0;    // exclusive
}

__global__ __launch_bounds__(256) void k_scan_pass3(int* __restrict__ P, const int* __restrict__ psum){
  __shared__ int sA[256], sB[256];
  int t = threadIdx.x;
  int base = blockIdx.x*1024 + t*4;
  int4 v = *(const int4*)&P[base];
  int tsum = v.x + v.y + v.z + v.w;
  sA[t] = tsum;
  __syncthreads();
  int* src = sA; int* dst = sB;
  for(int ofs=1; ofs<256; ofs<<=1){
    int x = src[t];
    if(t >= ofs) x += src[t-ofs];
    dst[t] = x;
    __syncthreads();
    int* tmp = src; src = dst; dst = tmp;
  }
  int excl = psum[blockIdx.x] + src[t] - tsum;   // exclusive across whole array
  int4 o;
  o.x = excl;
  o.y = o.x + v.x;
  o.z = o.y + v.y;
  o.w = o.z + v.z;
  *(int4*)&P[base] = o;
}

// After k_fill, P[c] holds END offset of row c; begin(c) = c ? P[c-1] : 0.
__global__ __launch_bounds__(256) void k_fill(const int* __restrict__ ci, const int* __restrict__ li,
    int* __restrict__ Pc, int* __restrict__ Pl, int* __restrict__ clit, int* __restrict__ lcl, int ne){
  int e = blockIdx.x*256 + threadIdx.x;
  if(e < ne){
    int c = ci[e], l = li[e];
    clit[atomicAdd(&Pc[c], 1)] = l;
    lcl [atomicAdd(&Pl[l], 1)] = c;
  }
}

// ------ clause side: CSR gather + COMPENSATED bf16 MFMA MLP 256->256->128
// 256 thr, 32 clauses/block, xs[2][32][264] hi/lo planes.
// Gather: 2 groups of 4 INTERLEAVED row-chains per wave (4 loads in flight,
// mask-FMA predication; per-row edge order preserved -> bitwise identical).
__global__ __launch_bounds__(256) void k_clause_fused(
    const int* __restrict__ Pc, const int* __restrict__ clit,
    const float* __restrict__ Lh,
    const short* __restrict__ W1h, const short* __restrict__ W1l, const float* __restrict__ b1,
    const short* __restrict__ W2h, const short* __restrict__ W2l, const float* __restrict__ b2,
    float* __restrict__ Y){
  __shared__ short xs[2][32][264];
  __shared__ int rng[33];
  const int t = threadIdx.x;
  const int r0 = blockIdx.x * 32;

  if(t < 33) rng[t] = (r0 + t == 0) ? 0 : Pc[r0 + t - 1];
  __syncthreads();

  const int lane = t & 63, wv = t >> 6;
  { // gather: lanes 0-31 direct half, 32-63 flipped; float4/lane
    const int half = lane >> 5, f4 = (lane & 31) * 4;
    #pragma unroll
    for(int g=0; g<2; g++){
      const int rb4 = wv*8 + g*4;
      const int e0=rng[rb4+0], d0=rng[rb4+1]-e0;
      const int e1=rng[rb4+1], d1=rng[rb4+2]-e1;
      const int e2=rng[rb4+2], d2=rng[rb4+3]-e2;
      const int e3=rng[rb4+3], d3=rng[rb4+4]-e3;
      float4 a0=make_float4(0.f,0.f,0.f,0.f), a1=a0, a2=a0, a3=a0;
      int l0=(d0>0)?clit[e0]:0, l1=(d1>0)?clit[e1]:0;
      int l2=(d2>0)?clit[e2]:0, l3=(d3>0)?clit[e3]:0;
      const int md = imax(imax(d0,d1), imax(d2,d3));
      for(int s=0; s<md; s++){
        int s0 = half ? ((l0<HALFL)?l0+HALFL:l0-HALFL) : l0;
        int s1 = half ? ((l1<HALFL)?l1+HALFL:l1-HALFL) : l1;
        int s2 = half ? ((l2<HALFL)?l2+HALFL:l2-HALFL) : l2;
        int s3 = half ? ((l3<HALFL)?l3+HALFL:l3-HALFL) : l3;
        float4 v0 = *(const float4*)&Lh[(size_t)s0*128 + f4];
        float4 v1 = *(const float4*)&Lh[(size_t)s1*128 + f4];
        float4 v2 = *(const float4*)&Lh[(size_t)s2*128 + f4];
        float4 v3 = *(const float4*)&Lh[(size_t)s3*128 + f4];
        int p0=(s+1<d0)?clit[e0+s+1]:0;        // prefetch next indices
        int p1=(s+1<d1)?clit[e1+s+1]:0;
        int p2=(s+1<d2)?clit[e2+s+1]:0;
        int p3=(s+1<d3)?clit[e3+s+1]:0;
        float m0=(s<d0)?1.f:0.f, m1=(s<d1)?1.f:0.f;
        float m2=(s<d2)?1.f:0.f, m3=(s<d3)?1.f:0.f;
        a0.x=fmaf(m0,v0.x,a0.x); a0.y=fmaf(m0,v0.y,a0.y); a0.z=fmaf(m0,v0.z,a0.z); a0.w=fmaf(m0,v0.w,a0.w);
        a1.x=fmaf(m1,v1.x,a1.x); a1.y=fmaf(m1,v1.y,a1.y); a1.z=fmaf(m1,v1.z,a1.z); a1.w=fmaf(m1,v1.w,a1.w);
        a2.x=fmaf(m2,v2.x,a2.x); a2.y=fmaf(m2,v2.y,a2.y); a2.z=fmaf(m2,v2.z,a2.z); a2.w=fmaf(m2,v2.w,a2.w);
        a3.x=fmaf(m3,v3.x,a3.x); a3.y=fmaf(m3,v3.y,a3.y); a3.z=fmaf(m3,v3.z,a3.z); a3.w=fmaf(m3,v3.w,a3.w);
        l0=p0; l1=p1; l2=p2; l3=p3;
      }
      float4 aa[4] = {a0, a1, a2, a3};
      #pragma unroll
      for(int i=0;i<4;i++){
        float4 a = aa[i];
        unsigned short hx=f2b(a.x), hy=f2b(a.y), hz=f2b(a.z), hw=f2b(a.w);
        unsigned short lx=f2b(a.x-b2f(hx)), ly=f2b(a.y-b2f(hy));
        unsigned short lz=f2b(a.z-b2f(hz)), lw=f2b(a.w-b2f(hw));
        *(uint2*)&xs[0][rb4+i][half*128 + f4] =
          make_uint2(((unsigned int)hy<<16)|hx, ((unsigned int)hw<<16)|hz);
        *(uint2*)&xs[1][rb4+i][half*128 + f4] =
          make_uint2(((unsigned int)ly<<16)|lx, ((unsigned int)lw<<16)|lz);
      }
    }
  }
  __syncthreads();

  const int rt  = wv & 1;
  const int ntb = (wv >> 1) * 8;
  const int am  = rt*16 + (lane & 15);
  const int ak  = (lane >> 4) * 8;

  // layer 1: 256 -> 256
  f32x4 acc[8];
  #pragma unroll
  for(int ntl=0; ntl<8; ntl++){
    float bv = b1[(ntb+ntl)*16 + (lane & 15)];
    acc[ntl] = (f32x4){bv, bv, bv, bv};
  }
  {
    const short8* Bh = (const short8*)W1h;
    const short8* Bl = (const short8*)W1l;
    #pragma unroll
    for(int kt=0; kt<8; kt++){
      short8 ah = *(const short8*)&xs[0][am][kt*32 + ak];
      short8 al = *(const short8*)&xs[1][am][kt*32 + ak];
      #pragma unroll
      for(int ntl=0; ntl<8; ntl++){
        int g = ntb + ntl;
        short8 bh = Bh[(g*8 + kt)*64 + lane];
        short8 bl = Bl[(g*8 + kt)*64 + lane];
        acc[ntl] = __builtin_amdgcn_mfma_f32_16x16x32_bf16(ah, bh, acc[ntl], 0, 0, 0);
        acc[ntl] = __builtin_amdgcn_mfma_f32_16x16x32_bf16(ah, bl, acc[ntl], 0, 0, 0);
        acc[ntl] = __builtin_amdgcn_mfma_f32_16x16x32_bf16(al, bh, acc[ntl], 0, 0, 0);
      }
    }
  }
  __syncthreads();
  #pragma unroll
  for(int ntl=0; ntl<8; ntl++){
    int col = (ntb + ntl)*16 + (lane & 15);
    int rowb = rt*16 + ((lane >> 4) << 2);
    #pragma unroll
    for(int reg=0; reg<4; reg++){
      float v = fmaxf(acc[ntl][reg], 0.f);
      unsigned short hi = f2b(v);
      xs[0][rowb + reg][col] = (short)hi;
      xs[1][rowb + reg][col] = (short)f2b(v - b2f(hi));
    }
  }
  __syncthreads();

  // layer 2: 256 -> 128
  const int ntb2 = (wv >> 1) * 4;
  f32x4 o4[4];
  #pragma unroll
  for(int ntl=0; ntl<4; ntl++){
    float bv = b2[(ntb2+ntl)*16 + (lane & 15)];
    o4[ntl] = (f32x4){bv, bv, bv, bv};
  }
  {
    const short8* Bh = (const short8*)W2h;
    const short8* Bl = (const short8*)W2l;
    #pragma unroll
    for(int kt=0; kt<8; kt++){
      short8 ah = *(const short8*)&xs[0][am][kt*32 + ak];
      short8 al = *(const short8*)&xs[1][am][kt*32 + ak];
      #pragma unroll
      for(int ntl=0; ntl<4; ntl++){
        int g = ntb2 + ntl;
        short8 bh = Bh[(g*8 + kt)*64 + lane];
        short8 bl = Bl[(g*8 + kt)*64 + lane];
        o4[ntl] = __builtin_amdgcn_mfma_f32_16x16x32_bf16(ah, bh, o4[ntl], 0, 0, 0);
        o4[ntl] = __builtin_amdgcn_mfma_f32_16x16x32_bf16(ah, bl, o4[ntl], 0, 0, 0);
        o4[ntl] = __builtin_amdgcn_mfma_f32_16x16x32_bf16(al, bh, o4[ntl], 0, 0, 0);
      }
    }
  }
  #pragma unroll
  for(int ntl=0; ntl<4; ntl++){
    int col = (ntb2 + ntl)*16 + (lane & 15);
    int rowb = r0 + rt*16 + ((lane >> 4) << 2);
    #pragma unroll
    for(int reg=0; reg<4; reg++)
      Y[(size_t)(rowb + reg)*128 + col] = o4[ntl][reg];
  }
}

// ---------------------------------------------------------------- col stats
__global__ __launch_bounds__(256) void k_colstats(const float* __restrict__ C, float* __restrict__ st){
  const int t = threadIdx.x, col = t & 127, h = t >> 7;
  float s = 0.f, s2 = 0.f;
  for(int r = blockIdx.x*2 + h; r < NCL; r += 1024){   // grid = 512 blocks
    float v = C[(size_t)r*128 + col];
    s += v; s2 += v*v;
  }
  __shared__ float red[256];
  red[t] = s; __syncthreads();
  if(t < 128) atomicAdd(&st[col], red[t] + red[t+128]);
  __syncthreads();
  red[t] = s2; __syncthreads();
  if(t < 128) atomicAdd(&st[128+col], red[t] + red[t+128]);
}

__global__ void k_finstats(float* st){
  int j = threadIdx.x;
  if(j < 128){
    const float n = (float)NCL;
    float mean = st[j]/n;
    float var = (st[128+j] - n*mean*mean) / (n - 1.f);   // ddof=1
    var = fmaxf(var, 0.f);
    st[256+j] = mean;
    st[384+j] = 1.f/(sqrtf(var) + 1e-10f);
  }
}

// -- literal side: gather(normalized) + COMPENSATED bf16 MFMA 128->128->128
//    + 0.1*residual + LayerNorm. 256 thr, 32 lits/block.
// Gather: 4 INTERLEAVED row-chains per half-wave.
__global__ __launch_bounds__(256) void k_lit_fused(
    const int* __restrict__ Pl, const int* __restrict__ lcl,
    const float* __restrict__ C, const float* __restrict__ st,
    const short* __restrict__ W1h, const short* __restrict__ W1l, const float* __restrict__ b1,
    const short* __restrict__ W2h, const short* __restrict__ W2l, const float* __restrict__ b2,
    const float* __restrict__ lng, const float* __restrict__ lnb, float* __restrict__ Lh){
  __shared__ short xs[2][32][136];
  __shared__ int rng[33];
  float* ys = (float*)&xs[0][0][0];          // [32][132] fp32, aliases xs
  const int t = threadIdx.x;
  const int r0 = blockIdx.x * 32;

  if(t < 33) rng[t] = (r0 + t == 0) ? 0 : Pl[r0 + t - 1];
  __syncthreads();

  const int lane = t & 63, wv = t >> 6;
  { // gather: half-wave rows wv*8+half*4 .. +3, interleaved; f4/lane covers 128
    const int half = lane >> 5, f4 = (lane & 31) * 4;
    float4 mean4 = *(const float4*)&st[256+f4];
    float4 isd4  = *(const float4*)&st[384+f4];
    const int rb4 = wv*8 + half*4;
    const int e0=rng[rb4+0], d0=rng[rb4+1]-e0;
    const int e1=rng[rb4+1], d1=rng[rb4+2]-e1;
    const int e2=rng[rb4+2], d2=rng[rb4+3]-e2;
    const int e3=rng[rb4+3], d3=rng[rb4+4]-e3;
    float4 a0=make_float4(0.f,0.f,0.f,0.f), a1=a0, a2=a0, a3=a0;
    int l0=(d0>0)?lcl[e0]:0, l1=(d1>0)?lcl[e1]:0;
    int l2=(d2>0)?lcl[e2]:0, l3=(d3>0)?lcl[e3]:0;
    const int md = imax(imax(d0,d1), imax(d2,d3));
    for(int s=0; s<md; s++){
      float4 v0 = *(const float4*)&C[(size_t)l0*128 + f4];
      float4 v1 = *(const float4*)&C[(size_t)l1*128 + f4];
      float4 v2 = *(const float4*)&C[(size_t)l2*128 + f4];
      float4 v3 = *(const float4*)&C[(size_t)l3*128 + f4];
      int p0=(s+1<d0)?lcl[e0+s+1]:0;
      int p1=(s+1<d1)?lcl[e1+s+1]:0;
      int p2=(s+1<d2)?lcl[e2+s+1]:0;
      int p3=(s+1<d3)?lcl[e3+s+1]:0;
      float m0=(s<d0)?1.f:0.f, m1=(s<d1)?1.f:0.f;
      float m2=(s<d2)?1.f:0.f, m3=(s<d3)?1.f:0.f;
      a0.x=fmaf(m0,v0.x,a0.x); a0.y=fmaf(m0,v0.y,a0.y); a0.z=fmaf(m0,v0.z,a0.z); a0.w=fmaf(m0,v0.w,a0.w);
      a1.x=fmaf(m1,v1.x,a1.x); a1.y=fmaf(m1,v1.y,a1.y); a1.z=fmaf(m1,v1.z,a1.z); a1.w=fmaf(m1,v1.w,a1.w);
      a2.x=fmaf(m2,v2.x,a2.x); a2.y=fmaf(m2,v2.y,a2.y); a2.z=fmaf(m2,v2.z,a2.z); a2.w=fmaf(m2,v2.w,a2.w);
      a3.x=fmaf(m3,v3.x,a3.x); a3.y=fmaf(m3,v3.y,a3.y); a3.z=fmaf(m3,v3.z,a3.z); a3.w=fmaf(m3,v3.w,a3.w);
      l0=p0; l1=p1; l2=p2; l3=p3;
    }
    float4 aa[4] = {a0, a1, a2, a3};
    float dd[4] = {(float)d0, (float)d1, (float)d2, (float)d3};
    #pragma unroll
    for(int i=0;i<4;i++){
      float4 a = aa[i];
      float dg = dd[i];
      a.x = (a.x - dg*mean4.x)*isd4.x; a.y = (a.y - dg*mean4.y)*isd4.y;
      a.z = (a.z - dg*mean4.z)*isd4.z; a.w = (a.w - dg*mean4.w)*isd4.w;
      unsigned short hx=f2b(a.x), hy=f2b(a.y), hz=f2b(a.z), hw=f2b(a.w);
      unsigned short lx=f2b(a.x-b2f(hx)), ly=f2b(a.y-b2f(hy));
      unsigned short lz=f2b(a.z-b2f(hz)), lw=f2b(a.w-b2f(hw));
      *(uint2*)&xs[0][rb4+i][f4] = make_uint2(((unsigned int)hy<<16)|hx, ((unsigned int)hw<<16)|hz);
      *(uint2*)&xs[1][rb4+i][f4] = make_uint2(((unsigned int)ly<<16)|lx, ((unsigned int)lw<<16)|lz);
    }
  }
  __syncthreads();

  const int rt  = wv & 1;                 // row-tile (rows rt*16..+15)
  const int ntb = (wv >> 1) * 4;          // 4 n-tiles per wave-pair (128 cols)
  const int am  = rt*16 + (lane & 15);
  const int ak  = (lane >> 4) * 8;

  // layer 1: 128 -> 128 (kt in 0..3)
  f32x4 acc[4];
  #pragma unroll
  for(int ntl=0; ntl<4; ntl++){
    float bv = b1[(ntb+ntl)*16 + (lane & 15)];
    acc[ntl] = (f32x4){bv, bv, bv, bv};
  }
  {
    const short8* Bh = (const short8*)W1h;
    const short8* Bl = (const short8*)W1l;
    #pragma unroll
    for(int kt=0; kt<4; kt++){
      short8 ah = *(const short8*)&xs[0][am][kt*32 + ak];
      short8 al = *(const short8*)&xs[1][am][kt*32 + ak];
      #pragma unroll
      for(int ntl=0; ntl<4; ntl++){
        int g = ntb + ntl;
        short8 bh = Bh[(g*4 + kt)*64 + lane];
        short8 bl = Bl[(g*4 + kt)*64 + lane];
        acc[ntl] = __builtin_amdgcn_mfma_f32_16x16x32_bf16(ah, bh, acc[ntl], 0, 0, 0);
        acc[ntl] = __builtin_amdgcn_mfma_f32_16x16x32_bf16(ah, bl, acc[ntl], 0, 0, 0);
        acc[ntl] = __builtin_amdgcn_mfma_f32_16x16x32_bf16(al, bh, acc[ntl], 0, 0, 0);
      }
    }
  }
  __syncthreads();
  // hidden: ReLU -> hi/lo bf16, overwrite xs
  #pragma unroll
  for(int ntl=0; ntl<4; ntl++){
    int col = (ntb + ntl)*16 + (lane & 15);
    int rowb = rt*16 + ((lane >> 4) << 2);
    #pragma unroll
    for(int reg=0; reg<4; reg++){
      float v = fmaxf(acc[ntl][reg], 0.f);
      unsigned short hi = f2b(v);
      xs[0][rowb + reg][col] = (short)hi;
      xs[1][rowb + reg][col] = (short)f2b(v - b2f(hi));
    }
  }
  __syncthreads();

  // layer 2: 128 -> 128 (A-frags loaded upfront, then xs is reused as ys)
  short8 a2h[4], a2l[4];
  #pragma unroll
  for(int kt=0; kt<4; kt++){
    a2h[kt] = *(const short8*)&xs[0][am][kt*32 + ak];
    a2l[kt] = *(const short8*)&xs[1][am][kt*32 + ak];
  }
  __syncthreads();                         // all xs reads done -> ys writable
  f32x4 o4[4];
  #pragma unroll
  for(int ntl=0; ntl<4; ntl++){
    float bv = b2[(ntb+ntl)*16 + (lane & 15)];
    o4[ntl] = (f32x4){bv, bv, bv, bv};
  }
  {
    const short8* Bh = (const short8*)W2h;
    const short8* Bl = (const short8*)W2l;
    #pragma unroll
    for(int kt=0; kt<4; kt++){
      #pragma unroll
      for(int ntl=0; ntl<4; ntl++){
        int g = ntb + ntl;
        short8 bh = Bh[(g*4 + kt)*64 + lane];
        short8 bl = Bl[(g*4 + kt)*64 + lane];
        o4[ntl] = __builtin_amdgcn_mfma_f32_16x16x32_bf16(a2h[kt], bh, o4[ntl], 0, 0, 0);
        o4[ntl] = __builtin_amdgcn_mfma_f32_16x16x32_bf16(a2h[kt], bl, o4[ntl], 0, 0, 0);
        o4[ntl] = __builtin_amdgcn_mfma_f32_16x16x32_bf16(a2l[kt], bh, o4[ntl], 0, 0, 0);
      }
    }
  }
  #pragma unroll
  for(int ntl=0; ntl<4; ntl++){
    int col = (ntb + ntl)*16 + (lane & 15);
    int rowb = rt*16 + ((lane >> 4) << 2);
    #pragma unroll
    for(int reg=0; reg<4; reg++)
      ys[(rowb + reg)*132 + col] = o4[ntl][reg];
  }
  __syncthreads();

  { // residual + LayerNorm: 8 threads per row, 16 cols each
    const int r  = t >> 3;                 // 0..31
    const int cg = (t & 7) * 16;
    size_t row = (size_t)(r0 + r);
    float y[16];
    #pragma unroll
    for(int jj=0; jj<16; jj+=4){
      float4 v = *(const float4*)&ys[r*132 + cg + jj];
      float4 la = *(const float4*)&Lh[row*128 + cg + jj];
      y[jj]   = v.x + 0.1f*la.x; y[jj+1] = v.y + 0.1f*la.y;
      y[jj+2] = v.z + 0.1f*la.z; y[jj+3] = v.w + 0.1f*la.w;
    }
    float s = 0.f, s2 = 0.f;
    #pragma unroll
    for(int jj=0; jj<16; jj++){ s += y[jj]; s2 += y[jj]*y[jj]; }
    #pragma unroll
    for(int m=1; m<8; m<<=1){ s += __shfl_xor(s,m,64); s2 += __shfl_xor(s2,m,64); }
    float mean = s*(1.f/128.f);
    float var  = s2*(1.f/128.f) - mean*mean;
    float rs   = rsqrtf(fmaxf(var, 0.f) + 1e-5f);
    #pragma unroll
    for(int jj=0; jj<16; jj+=4){
      float4 gv = *(const float4*)&lng[cg + jj];
      float4 bv = *(const float4*)&lnb[cg + jj];
      *(float4*)&Lh[row*128 + cg + jj] = make_float4(
        (y[jj]  -mean)*rs*gv.x + bv.x, (y[jj+1]-mean)*rs*gv.y + bv.y,
        (y[jj+2]-mean)*rs*gv.z + bv.z, (y[jj+3]-mean)*rs*gv.w + bv.w);
    }
  }
}

// ---------------------------------------------------------------- heads
__global__ __launch_bounds__(64) void k_head_v(const float* __restrict__ Lh,
    const float* __restrict__ W1d, const float* __restrict__ b1d, const float* __restrict__ W2d, const float* __restrict__ b2d,
    const float* __restrict__ W1c, const float* __restrict__ b1c, const float* __restrict__ W2c, const float* __restrict__ b2c,
    float* __restrict__ out){
  __shared__ float xs[8][256];
  const int t = threadIdx.x;
  const size_t v0 = (size_t)blockIdx.x * 8;
  #pragma unroll
  for(int r=0;r<8;r++){
    xs[r][t]     = Lh[(v0+r)*128 + t];
    xs[r][t+64]  = Lh[(v0+r)*128 + t + 64];
    xs[r][t+128] = Lh[(v0+r+HALFL)*128 + t];
    xs[r][t+192] = Lh[(v0+r+HALFL)*128 + t + 64];
  }
  __syncthreads();
  for(int hd=0; hd<2; hd++){
    const float* W1 = hd ? W1c : W1d;
    const float* b1 = hd ? b1c : b1d;
    const float* W2 = hd ? W2c : W2d;
    const float* b2 = hd ? b2c : b2d;
    float acc[8][4];
    #pragma unroll
    for(int c=0;c<4;c++){
      float bvv = b1[t + 64*c];
      #pragma unroll
      for(int r=0;r<8;r++) acc[r][c]=bvv;
    }
    for(int k=0;k<256;k+=4){
      float w[4][4];
      #pragma unroll
      for(int kk=0;kk<4;kk++)
        #pragma unroll
        for(int c=0;c<4;c++) w[kk][c] = W1[(size_t)(k+kk)*256 + t + 64*c];
      #pragma unroll
      for(int r=0;r<8;r++){
        float4 tv = *(const float4*)&xs[r][k];
        #pragma unroll
        for(int c=0;c<4;c++)
          acc[r][c] += tv.x*w[0][c] + tv.y*w[1][c] + tv.z*w[2][c] + tv.w*w[3][c];
      }
    }
    float w2[4];
    #pragma unroll
    for(int c=0;c<4;c++) w2[c] = W2[t + 64*c];
    float bb = b2[0];
    #pragma unroll
    for(int r=0;r<8;r++){
      float o = fmaxf(acc[r][0],0.f)*w2[0] + fmaxf(acc[r][1],0.f)*w2[1]
              + fmaxf(acc[r][2],0.f)*w2[2] + fmaxf(acc[r][3],0.f)*w2[3];
      #pragma unroll
      for(int m=1;m<64;m<<=1) o += __shfl_xor(o,m,64);
      if(t == 0) out[(size_t)hd*NVAR + v0 + r] = o + bb;
    }
  }
}

// 64 thr, 8 clauses/block; normalizes C on load.
__global__ __launch_bounds__(64) void k_head_c(const float* __restrict__ C,
    const float* __restrict__ st,
    const float* __restrict__ W1, const float* __restrict__ b1,
    const float* __restrict__ W2, const float* __restrict__ b2,
    float* __restrict__ out){
  __shared__ float xs[8][128];
  const int t = threadIdx.x;
  const size_t c0 = (size_t)blockIdx.x * 8;
  { float m0 = st[256+t], m1 = st[256+t+64];
    float i0 = st[384+t], i1 = st[384+t+64];
    #pragma unroll
    for(int r=0;r<8;r++){
      xs[r][t]    = (C[(c0+r)*128 + t]      - m0) * i0;
      xs[r][t+64] = (C[(c0+r)*128 + t + 64] - m1) * i1;
    }
  }
  __syncthreads();
  float a0[8], a1[8];
  float bv0 = b1[t], bv1 = b1[t+64];
  #pragma unroll
  for(int r=0;r<8;r++){ a0[r]=bv0; a1[r]=bv1; }
  for(int k=0;k<128;k+=4){
    float w0[4], w1[4];
    #pragma unroll
    for(int kk=0;kk<4;kk++){ w0[kk]=W1[(size_t)(k+kk)*128 + t]; w1[kk]=W1[(size_t)(k+kk)*128 + t + 64]; }
    #pragma unroll
    for(int r=0;r<8;r++){
      float4 tv = *(const float4*)&xs[r][k];
      a0[r] += tv.x*w0[0]+tv.y*w0[1]+tv.z*w0[2]+tv.w*w0[3];
      a1[r] += tv.x*w1[0]+tv.y*w1[1]+tv.z*w1[2]+tv.w*w1[3];
    }
  }
  float w2a = W2[t], w2b = W2[t+64];
  float bb = b2[0];
  #pragma unroll
  for(int r=0;r<8;r++){
    float o = fmaxf(a0[r],0.f)*w2a + fmaxf(a1[r],0.f)*w2b;
    #pragma unroll
    for(int m=1;m<64;m<<=1) o += __shfl_xor(o,m,64);
    if(t == 0) out[c0 + r] = o + bb;
  }
}

// ---------------------------------------------------------------- launch
extern "C" void kernel_launch(void* const* d_in, const int* in_sizes, int n_in,
                              void* d_out, int out_size, void* d_ws, size_t ws_size,
                              hipStream_t stream){
  const float* L0   = (const float*)d_in[0];
  const float* lng  = (const float*)d_in[1];
  const float* lnb  = (const float*)d_in[2];
  const float* CuW1 = (const float*)d_in[3];
  const float* Cub1 = (const float*)d_in[4];
  const float* CuW2 = (const float*)d_in[5];
  const float* Cub2 = (const float*)d_in[6];
  const float* LuW1 = (const float*)d_in[7];
  const float* Lub1 = (const float*)d_in[8];
  const float* LuW2 = (const float*)d_in[9];
  const float* Lub2 = (const float*)d_in[10];
  const float* VdW1 = (const float*)d_in[11];
  const float* Vdb1 = (const float*)d_in[12];
  const float* VdW2 = (const float*)d_in[13];
  const float* Vdb2 = (const float*)d_in[14];
  const float* VcW1 = (const float*)d_in[15];
  const float* Vcb1 = (const float*)d_in[16];
  const float* VcW2 = (const float*)d_in[17];
  const float* Vcb2 = (const float*)d_in[18];
  const float* CsW1 = (const float*)d_in[19];
  const float* Csb1 = (const float*)d_in[20];
  const float* CsW2 = (const float*)d_in[21];
  const float* Csb2 = (const float*)d_in[22];
  const int* cidx = (const int*)d_in[23];
  const int* lidx = (const int*)d_in[24];
  const int  ne   = in_sizes[23];

  float* ws   = (float*)d_ws;
  float* Lh   = ws;                        // 25,600,000 f32
  float* C    = ws + 25600000;             // 38,400,000 f32 -> end 64,000,000
  float* st   = ws + 64000000;             // 512: sum|sumsq|mean|isd
  short* W1h  = (short*)(ws + 64000512);   // 65,536 bf16
  short* W1l  = (short*)(ws + 64033280);   // 65,536 bf16
  short* W2h  = (short*)(ws + 64066048);   // 32,768 bf16
  short* W2l  = (short*)(ws + 64082432);   // 32,768 bf16
  short* W3h  = (short*)(ws + 64098816);   // 16,384 bf16 (LuW1 hi)
  short* W3l  = (short*)(ws + 64107008);   // 16,384 bf16
  short* W4h  = (short*)(ws + 64115200);   // 16,384 bf16 (LuW2 hi)
  short* W4l  = (short*)(ws + 64123392);   // 16,384 bf16
  int*   ib   = (int*)(ws + 64131584);     // int region
  int*   Pc   = ib;                        // PAD_C = 300,032
  int*   Pl   = ib + PAD_C;                // PAD_L = 200,704
  int*   clit = ib + PAD_C + PAD_L;        // 1,000,000
  int*   lcl  = clit + 1000000;            // 1,000,000
  int*   psum = lcl + 1000000;             // 512
  // total ws ~= 266.6 MB
  float* out = (float*)d_out;              // fp32: drat|core|c_core

  k_init_lh<<<100000, 256, 0, stream>>>(L0, Lh);
  k_pack_w<<<256, 256, 0, stream>>>(CuW1, W1h, W1l, 256, 256);
  k_pack_w<<<128, 256, 0, stream>>>(CuW2, W2h, W2l, 256, 128);
  k_pack_w<<<64, 256, 0, stream>>>(LuW1, W3h, W3l, 128, 128);
  k_pack_w<<<64, 256, 0, stream>>>(LuW2, W4h, W4l, 128, 128);

  // CSR build (counting sort both directions)
  k_zero4<<<489, 256, 0, stream>>>((float4*)Pc, (PAD_C + PAD_L)/4);
  k_hist<<<(ne+255)/256, 256, 0, stream>>>(cidx, lidx, Pc, Pl, ne);
  k_scan_pass1<<<NB_C, 256, 0, stream>>>(Pc, psum);
  k_scan_pass2<<<1, 512, 0, stream>>>(psum, NB_C);
  k_scan_pass3<<<NB_C, 256, 0, stream>>>(Pc, psum);
  k_scan_pass1<<<NB_L, 256, 0, stream>>>(Pl, psum);
  k_scan_pass2<<<1, 512, 0, stream>>>(psum, NB_L);
  k_scan_pass3<<<NB_L, 256, 0, stream>>>(Pl, psum);
  k_fill<<<(ne+255)/256, 256, 0, stream>>>(cidx, lidx, Pc, Pl, clit, lcl, ne);

  for(int hop=0; hop<4; hop++){
    k_zero4<<<1, 256, 0, stream>>>((float4*)st, 128);
    k_clause_fused<<<9375, 256, 0, stream>>>(Pc, clit, Lh, W1h, W1l, Cub1, W2h, W2l, Cub2, C);
    k_colstats<<<512, 256, 0, stream>>>(C, st);
    k_finstats<<<1, 128, 0, stream>>>(st);
    k_lit_fused<<<6250, 256, 0, stream>>>(Pl, lcl, C, st, W3h, W3l, Lub1, W4h, W4l, Lub2, lng, lnb, Lh);
  }
  k_head_v<<<12500, 64, 0, stream>>>(Lh, VdW1, Vdb1, VdW2, Vdb2, VcW1, Vcb1, VcW2, Vcb2, out);
  k_head_c<<<37500, 64, 0, stream>>>(C, st, CsW1, Csb1, CsW2, Csb2, out + 200000);
}